// Round 4
// baseline (363.763 us; speedup 1.0000x reference)
//
#include <hip/hip_runtime.h>
#include <hip/hip_bf16.h>

#define B 8
#define N 2048
#define BN (B*N)
#define KNBR 32
#define NKP 15
#define VCH 32   // n-chunks per batch in VLAD accumulation (32 -> 256 blocks)

#define ZERON 2632   // floats zeroed by k_prep tail: sumA(512)+outacc(2048)+ssq(64 pad)+cnt(8)

__device__ __forceinline__ float lrelu(float x){ return x > 0.f ? x : 0.1f*x; }
__device__ __forceinline__ unsigned umin_(unsigned a, unsigned b){ return __builtin_elementwise_min(a, b); }
__device__ __forceinline__ unsigned umax_(unsigned a, unsigned b){ return __builtin_elementwise_max(a, b); }

// MFMA fragment types (per guide: short8 = 8 bf16 = 4 VGPRs)
typedef __attribute__((ext_vector_type(8))) short bf16x8;
typedef __attribute__((ext_vector_type(4))) float fx4;

__device__ __forceinline__ short bfr(float f){
    union { __hip_bfloat16 h; short s; } u;
    u.h = __float2bfloat16(f);
    return u.s;
}
__device__ __forceinline__ unsigned pk2(float a, float b){
    return ((unsigned)(unsigned short)bfr(b) << 16) | (unsigned)(unsigned short)bfr(a);
}

// ---------------------------------------------------------------------------
// Fused weight prep: 3x wkT + 3x catT + 2x w1T, plus workspace zeroing tail
// (absorbs the old k_zero launch; zbuf spans sumA|outacc|ssq|cnt contiguously).
__global__ __launch_bounds__(256) void k_prep(
    const float* __restrict__ wk0, const float* __restrict__ wk1, const float* __restrict__ wk2,
    const float* __restrict__ w20, const float* __restrict__ ws0,
    const float* __restrict__ w21, const float* __restrict__ ws1,
    const float* __restrict__ w22, const float* __restrict__ ws2,
    const float* __restrict__ w1_1, const float* __restrict__ w1_2,
    short* __restrict__ wkT0, short* __restrict__ wkT1, short* __restrict__ wkT2,
    short* __restrict__ cat0, short* __restrict__ cat1, short* __restrict__ cat2,
    short* __restrict__ w1T1, short* __restrict__ w1T2,
    float* __restrict__ zbuf)
{
    const int i = blockIdx.x * 256 + threadIdx.x;
    if (i < 3*61440) {
        const int l = i / 61440, r = i % 61440;
        const int n = r / 960, k = r % 960;
        const float* wk = (l == 0) ? wk0 : (l == 1) ? wk1 : wk2;
        short* dst = (l == 0) ? wkT0 : (l == 1) ? wkT1 : wkT2;
        dst[r] = bfr(wk[k*64 + n]);
    } else {
        int j = i - 3*61440;
        if (j < 16384) {
            const int n = j / 128, k = j % 128;
            cat0[j] = bfr(k < 64 ? w20[k*128 + n] : ws0[(k-64)*128 + n]);
        } else if (j < 16384 + 24576) {
            j -= 16384;
            const int n = j / 192, k = j % 192;
            cat1[j] = bfr(k < 64 ? w21[k*128 + n] : ws1[(k-64)*128 + n]);
        } else if (j < 16384 + 49152) {
            j -= 16384 + 24576;
            const int n = j / 192, k = j % 192;
            cat2[j] = bfr(k < 64 ? w22[k*128 + n] : ws2[(k-64)*128 + n]);
        } else if (j < 16384 + 49152 + 8192) {
            j -= 16384 + 49152;
            const int n = j / 128, k = j % 128;
            w1T1[j] = bfr(w1_1[k*64 + n]);
        } else if (j < 16384 + 49152 + 16384) {
            j -= 16384 + 49152 + 8192;
            const int n = j / 128, k = j % 128;
            w1T2[j] = bfr(w1_2[k*64 + n]);
        } else {
            const int z = j - (16384 + 49152 + 16384);
            if (z < ZERON) zbuf[z] = 0.f;
        }
    }
}

// ---------------------------------------------------------------------------
// Compaction with wave-aggregated atomics (round-10 verified).
__global__ __launch_bounds__(256) void k_compact(
    const int* __restrict__ m, int* __restrict__ compact, int* __restrict__ cnt,
    int* __restrict__ idx)
{
    const int p = blockIdx.x * 256 + threadIdx.x;
    const int b = p >> 11, n = p & (N-1);
    const int lane = threadIdx.x & 63;
    const bool unm = (m[p] == 0);
    const unsigned long long mask = __ballot(unm);
    int base = 0;
    if (lane == 0) base = atomicAdd(&cnt[b], __popcll(mask));
    base = __shfl(base, 0, 64);
    if (unm) {
        const int pos = base + __popcll(mask & ((1ull << lane) - 1ull));
        compact[b*N + pos] = n;
    } else {
        #pragma unroll
        for (int k = 0; k < KNBR; k++) idx[(size_t)p*KNBR + k] = k;
    }
}

// ---------------------------------------------------------------------------
// PointNet (round-5 verified shape) + FUSED layer-0 unary (x1 = lrelu(feat@W1))
// — feat rows of this block's 32 points are block-resident, so the old
// standalone k_unary1<64> dispatch (+4MB HBM read) is folded in as stage 3.
// x1 is emitted directly as bf16 (the consumer MFMA is bf16 anyway).
__global__ __launch_bounds__(256) void k_pointnet(
    const float* __restrict__ x, const int* __restrict__ m,
    const float* __restrict__ w1, const float* __restrict__ b1,
    const float* __restrict__ w2, const float* __restrict__ b2,
    const float* __restrict__ wu,
    float* __restrict__ feat, float4* __restrict__ coords4,
    unsigned short* __restrict__ x1out)
{
    __shared__ float s_x[32][3];
    __shared__ __align__(16) float s_hT[64*40];
    __shared__ __align__(16) float s_fT[64*40];
    const int tid = threadIdx.x;
    const int pbase = blockIdx.x * 32;
    if (tid < 32) {
        const int p = pbase + tid;
        const float x0 = x[p*3+0], x1v = x[p*3+1], x2v = x[p*3+2];
        s_x[tid][0] = x0; s_x[tid][1] = x1v; s_x[tid][2] = x2v;
        const bool mm = (m[p] != 0);
        const float cx = mm ? 1e6f : x0, cy = mm ? 1e6f : x1v, cz = mm ? 1e6f : x2v;
        coords4[p] = make_float4(cx, cy, cz, cx*cx + cy*cy + cz*cz);
    }
    __syncthreads();
    const int w = tid >> 6, c = tid & 63;
    const int pb = w * 8;
    {
        const float w10 = w1[c], w11 = w1[64+c], w12 = w1[128+c], bb = b1[c];
        #pragma unroll
        for (int pl = 0; pl < 8; pl++) {
            float s = bb;
            s = fmaf(s_x[pb+pl][0], w10, s);
            s = fmaf(s_x[pb+pl][1], w11, s);
            s = fmaf(s_x[pb+pl][2], w12, s);
            s_hT[c*40 + pb + pl] = fmaxf(s, 0.f);
        }
    }
    {
        float acc[8];
        const float bb = b2[c];
        #pragma unroll
        for (int pl = 0; pl < 8; pl++) acc[pl] = bb;
        for (int j = 0; j < 64; j++) {
            const float wv = w2[j*64 + c];
            const float4 h0 = *(const float4*)&s_hT[j*40 + pb];
            const float4 h1 = *(const float4*)&s_hT[j*40 + pb + 4];
            acc[0] = fmaf(h0.x, wv, acc[0]); acc[1] = fmaf(h0.y, wv, acc[1]);
            acc[2] = fmaf(h0.z, wv, acc[2]); acc[3] = fmaf(h0.w, wv, acc[3]);
            acc[4] = fmaf(h1.x, wv, acc[4]); acc[5] = fmaf(h1.y, wv, acc[5]);
            acc[6] = fmaf(h1.z, wv, acc[6]); acc[7] = fmaf(h1.w, wv, acc[7]);
        }
        #pragma unroll
        for (int pl = 0; pl < 8; pl++) {
            const float fv = fmaxf(acc[pl], 0.f);
            feat[(size_t)(pbase + pb + pl)*64 + c] = fv;
            s_fT[c*40 + pb + pl] = fv;
        }
    }
    __syncthreads();
    // stage 3: x1 = lrelu(feat @ wu), bf16 out (identical loop order to old k_unary1)
    {
        float acc[8] = {0.f,0.f,0.f,0.f,0.f,0.f,0.f,0.f};
        for (int j = 0; j < 64; j++) {
            const float wv = wu[j*64 + c];
            const float4 f0 = *(const float4*)&s_fT[j*40 + pb];
            const float4 f1 = *(const float4*)&s_fT[j*40 + pb + 4];
            acc[0] = fmaf(f0.x, wv, acc[0]); acc[1] = fmaf(f0.y, wv, acc[1]);
            acc[2] = fmaf(f0.z, wv, acc[2]); acc[3] = fmaf(f0.w, wv, acc[3]);
            acc[4] = fmaf(f1.x, wv, acc[4]); acc[5] = fmaf(f1.y, wv, acc[5]);
            acc[6] = fmaf(f1.z, wv, acc[6]); acc[7] = fmaf(f1.w, wv, acc[7]);
        }
        #pragma unroll
        for (int pl = 0; pl < 8; pl++)
            x1out[(size_t)(pbase + pb + pl)*64 + c] = (unsigned short)bfr(lrelu(acc[pl]));
    }
}

// ---------------------------------------------------------------------------
// KNN — round-11 measured-best config (256 threads, 4 waves).
__global__ __launch_bounds__(256, 2) void k_knn(
    const float4* __restrict__ c4, const int* __restrict__ compact,
    const int* __restrict__ cnt, int* __restrict__ idx)
{
    const int b = blockIdx.x >> 9;
    const int slot0 = (blockIdx.x & 511) * 4;
    const int cn = cnt[b];
    if (slot0 >= cn) return;
    __shared__ float4 s_c[N];
    const int tid = threadIdx.x;
    const int w = tid >> 6, lane = tid & 63;
    for (int i = tid; i < N; i += 256) s_c[i] = c4[(size_t)b*N + i];
    __syncthreads();
    const int slot = slot0 + w;
    const bool active = slot < cn;
    const int n = active ? compact[b*N + slot] : 0;
    const float4 me = s_c[n];

    unsigned A[32];
    #pragma unroll
    for (int j = 0; j < 32; j++) {
        const float4 s = s_c[j*64 + lane];
        float d2 = me.w + s.w - 2.f*(me.x*s.x + me.y*s.y + me.z*s.z);
        d2 = fmaxf(d2, 0.f);
        A[j] = (__float_as_uint(d2) & 0xFFFFF800u) | (unsigned)(j*64 + lane);
    }
    #pragma unroll
    for (int k = 2; k <= 32; k <<= 1) {
        #pragma unroll
        for (int j = k >> 1; j > 0; j >>= 1) {
            #pragma unroll
            for (int i = 0; i < 32; i++) {
                const int l = i ^ j;
                if (l > i) {
                    const unsigned lo = umin_(A[i], A[l]);
                    const unsigned hi = umax_(A[i], A[l]);
                    const bool up = ((i & k) == 0);
                    A[i] = up ? lo : hi;
                    A[l] = up ? hi : lo;
                }
            }
        }
    }
    #pragma unroll
    for (int r = 0; r < 6; r++) {
        const int mask = 1 << r;
        #pragma unroll
        for (int i = 0; i < 16; i++) {
            const unsigned t1 = (unsigned)__shfl_xor((int)A[31-i], mask, 64);
            const unsigned t2 = (unsigned)__shfl_xor((int)A[i],    mask, 64);
            A[i]    = umin_(A[i],    t1);
            A[31-i] = umin_(A[31-i], t2);
        }
        if (r < 5) {
            #pragma unroll
            for (int j = 16; j > 0; j >>= 1) {
                #pragma unroll
                for (int i = 0; i < 32; i++) {
                    const int l = i ^ j;
                    if (l > i) {
                        const unsigned lo = umin_(A[i], A[l]);
                        A[l] = umax_(A[i], A[l]);
                        A[i] = lo;
                    }
                }
            }
        }
    }
    #pragma unroll
    for (int s = 16; s >= 1; s >>= 1) {
        #pragma unroll
        for (int i = 0; i < s; i++)
            A[i] = (lane & s) ? A[i+s] : A[i];
    }
    if (active && lane < 32)
        idx[(size_t)(b*N + n)*KNBR + lane] = (int)(A[0] & 0x7FFu);
}

// ---------------------------------------------------------------------------
// KPConv, 16 pts/block, 512 threads, all-MFMA (round-14 verified), plus
// FUSED phase 4 (when FUSE): next layer's x1 = lrelu(out @ W1).
// x1 is now bf16 end-to-end: phase-1 gather reads ushort rows (128B/row,
// fully coalesced) and packs with pure bit-ops — halves the dominant gather
// stream and drops the f32->bf16 cvt chain. x1 in/out are DIFFERENT buffers
// (ping-pong) to remove the previous in-place read/write race.
template<int CIN, bool FUSE>
__global__ __launch_bounds__(512) void k_kpconv(
    const unsigned short* __restrict__ x1, const float4* __restrict__ c4,
    const float* __restrict__ kp,
    const int* __restrict__ idx, const float* __restrict__ feat_in,
    const short* __restrict__ WkT, const short* __restrict__ WcatT,
    const short* __restrict__ W1T, unsigned short* __restrict__ x1out,
    float* __restrict__ out)
{
    constexpr int KC = 64 + CIN;   // phase-3 K extent
    constexpr int AS = 976;        // aggT row stride (shorts)
    constexpr int XS = 72;         // x2 row stride (shorts)
    constexpr int FS = CIN + 8;    // feat row stride (shorts)
    constexpr int PS = 65;         // partial row stride (floats)
    constexpr int FOS = 136;       // fused fout row stride (shorts)
    __shared__ __align__(16) short s_aggT[16*AS];      // 31232 B
    __shared__ __align__(16) unsigned s_un[11264];     // 45056 B union region
    __shared__ int   s_idx[512];
    __shared__ float skp[48];

    const int tid   = threadIdx.x;
    const int pbase = blockIdx.x * 16;
    const int brow  = pbase & ~(N-1);
    const int w = tid >> 6, lane = tid & 63;

    if (tid < NKP*3) skp[tid] = kp[tid];
    s_idx[tid] = idx[(size_t)pbase*KNBR + tid];
    __syncthreads();

    // ---- phase 1: wave w -> points 2w, 2w+1 (per-wave, no barriers) ----
    unsigned* xg  = s_un + w*1408;                    // [64 ch][18 dwords]
    short*    wbf = (short*)(s_un + w*1408 + 1152);   // [16 kp][32 nbr]

    for (int sub = 0; sub < 2; sub++) {
        const int pl = w*2 + sub;
        {
            const int k = lane & 31, h = lane >> 5;
            const float4 cp = c4[pbase + pl];
            const float4 cn = c4[brow + s_idx[pl*KNBR + k]];
            const float dx = cn.x - cp.x, dy = cn.y - cp.y, dz = cn.z - cp.z;
            #pragma unroll
            for (int j = 0; j < 8; j++) {
                const int kpi = h*8 + j;
                if (kpi < NKP) {
                    const float ex = dx - skp[kpi*3], ey = dy - skp[kpi*3+1], ez = dz - skp[kpi*3+2];
                    const float dist = sqrtf(ex*ex + ey*ey + ez*ez);
                    wbf[kpi*32 + k] = bfr(fmaxf(0.f, 1.f - dist*2.f));
                }
            }
        }
        {
            unsigned short g[KNBR];
            #pragma unroll
            for (int k = 0; k < KNBR; k++)
                g[k] = x1[(size_t)(brow + s_idx[pl*KNBR + k])*64 + lane];
            #pragma unroll
            for (int i = 0; i < 16; i++)
                xg[lane*18 + i] = (unsigned)g[2*i] | ((unsigned)g[2*i+1] << 16);
        }
        {
            const int n = lane & 15, q = lane >> 4;
            const bf16x8 bw = *(const bf16x8*)&wbf[n*32 + q*8];
            #pragma unroll
            for (int t = 0; t < 4; t++) {
                union { unsigned u[4]; bf16x8 v; } af;
                const unsigned* src = &xg[(t*16 + n)*18 + q*4];
                af.u[0] = src[0]; af.u[1] = src[1]; af.u[2] = src[2]; af.u[3] = src[3];
                fx4 d = {0.f,0.f,0.f,0.f};
                d = __builtin_amdgcn_mfma_f32_16x16x32_bf16(af.v, bw, d, 0, 0, 0);
                if (n < NKP) {
                    const uint2 o = make_uint2(pk2(d[0], d[1]), pk2(d[2], d[3]));
                    *(uint2*)&s_aggT[pl*AS + n*64 + t*16 + q*4] = o;
                }
            }
        }
    }
    __syncthreads();   // phase-1 region dead; union re-partitioned:

    short* s_x2bf   = (short*)s_un;                        // [16][XS]
    short* s_featbf = (short*)s_un + 16*XS;                // [16][FS]
    float* s_part   = (float*)((char*)s_un + 6656);        // [2][16][PS]

    for (int i = tid; i < 16*CIN; i += 512) {
        const int p = i / CIN, j = i % CIN;
        s_featbf[p*FS + j] = bfr(feat_in[(size_t)pbase*CIN + i]);
    }

    const int nlane = lane & 15, q = lane >> 4;
    // phase 2: x2 = lrelu(agg @ Wk). wave w -> col-tile (w&3), K-half (w>>2).
    {
        const int ct = w & 3, kh = w >> 2;
        fx4 acc = {0.f,0.f,0.f,0.f};
        const short* arow = &s_aggT[nlane*AS + kh*480];
        const short* brw  = &WkT[(size_t)(ct*16 + nlane)*960 + kh*480];
        for (int t = 0; t < 15; t++) {
            const int k0 = t*32 + q*8;
            const bf16x8 af = *(const bf16x8*)&arow[k0];
            const bf16x8 bf = *(const bf16x8*)&brw[k0];
            acc = __builtin_amdgcn_mfma_f32_16x16x32_bf16(af, bf, acc, 0, 0, 0);
        }
        float* pp = s_part + kh*(16*PS);
        #pragma unroll
        for (int r = 0; r < 4; r++)
            pp[(q*4+r)*PS + ct*16 + nlane] = acc[r];
    }
    __syncthreads();
    for (int i = tid; i < 1024; i += 512) {
        const int pt = i >> 6, c = i & 63;
        const float v = s_part[pt*PS + c] + s_part[16*PS + pt*PS + c];
        s_x2bf[pt*XS + c] = bfr(lrelu(v));
    }
    __syncthreads();

    // phase 3: out = lrelu([x2|feat] @ [W2;Ws]). wave w -> cols [16w,16w+16).
    fx4 acc0 = {0.f,0.f,0.f,0.f};
    {
        const short* b0r = &WcatT[(size_t)(w*16 + nlane)*KC];
        const short* xrow = &s_x2bf[nlane*XS];
        const short* frow = &s_featbf[nlane*FS];
        #pragma unroll
        for (int t = 0; t < KC/32; t++) {
            const int k0 = t*32 + q*8;
            const short* src = (t < 2) ? &xrow[k0] : &frow[k0 - 64];
            const bf16x8 af = *(const bf16x8*)src;
            const bf16x8 b0 = *(const bf16x8*)&b0r[k0];
            acc0 = __builtin_amdgcn_mfma_f32_16x16x32_bf16(af, b0, acc0, 0, 0, 0);
        }
        #pragma unroll
        for (int r = 0; r < 4; r++)
            out[(size_t)(pbase + q*4 + r)*128 + w*16 + nlane] = lrelu(acc0[r]);
    }

    if (FUSE) {
        // phase 4: x1out = lrelu(out @ W1) for the NEXT layer, in-block.
        __syncthreads();   // all phase-3 LDS reads done; re-alias s_un
        short* s_fout = (short*)s_un;   // [16][FOS]
        #pragma unroll
        for (int r = 0; r < 4; r++)
            s_fout[(q*4 + r)*FOS + w*16 + nlane] = bfr(lrelu(acc0[r]));
        __syncthreads();
        if (w < 4) {
            fx4 acc = {0.f,0.f,0.f,0.f};
            const short* arow = &s_fout[nlane*FOS];
            const short* brw  = &W1T[(size_t)(w*16 + nlane)*128];
            #pragma unroll
            for (int t = 0; t < 4; t++) {
                const int k0 = t*32 + q*8;
                const bf16x8 af = *(const bf16x8*)&arow[k0];
                const bf16x8 bf = *(const bf16x8*)&brw[k0];
                acc = __builtin_amdgcn_mfma_f32_16x16x32_bf16(af, bf, acc, 0, 0, 0);
            }
            #pragma unroll
            for (int r = 0; r < 4; r++)
                x1out[(size_t)(pbase + q*4 + r)*64 + w*16 + nlane] =
                    (unsigned short)bfr(lrelu(acc[r]));
        }
    }
}

// ---------------------------------------------------------------------------
__global__ __launch_bounds__(256) void k_vlad_a(
    const float* __restrict__ f, const float* __restrict__ wa,
    const int* __restrict__ m, float* __restrict__ a, float* __restrict__ sumA)
{
    __shared__ __align__(16) float s_fT[128*36 + 8];
    __shared__ float s_m[32];
    const int tid = threadIdx.x;
    const int pbase = blockIdx.x * 32;
    const int b = pbase >> 11;
    for (int i = tid; i < 32*128; i += 256) {
        const int p = i >> 7, j = i & 127;
        s_fT[j*36 + p] = f[(size_t)pbase*128 + i];
    }
    if (tid < 32) s_m[tid] = (m[pbase + tid] != 0) ? 0.f : 1.f;
    __syncthreads();
    const int w = tid >> 6, kc = tid & 63;
    const int pb = w * 8;
    float acc[8] = {0.f,0.f,0.f,0.f,0.f,0.f,0.f,0.f};
    for (int j = 0; j < 128; j++) {
        const float wv = wa[j*64 + kc];
        const float4 f0 = *(const float4*)&s_fT[j*36 + pb];
        const float4 f1 = *(const float4*)&s_fT[j*36 + pb + 4];
        acc[0] = fmaf(f0.x, wv, acc[0]); acc[1] = fmaf(f0.y, wv, acc[1]);
        acc[2] = fmaf(f0.z, wv, acc[2]); acc[3] = fmaf(f0.w, wv, acc[3]);
        acc[4] = fmaf(f1.x, wv, acc[4]); acc[5] = fmaf(f1.y, wv, acc[5]);
        acc[6] = fmaf(f1.z, wv, acc[6]); acc[7] = fmaf(f1.w, wv, acc[7]);
    }
    float part = 0.f;
    #pragma unroll
    for (int pl = 0; pl < 8; pl++) {
        float mx = acc[pl];
        #pragma unroll
        for (int off = 32; off > 0; off >>= 1) mx = fmaxf(mx, __shfl_xor(mx, off, 64));
        const float e = expf(acc[pl] - mx);
        float se = e;
        #pragma unroll
        for (int off = 32; off > 0; off >>= 1) se += __shfl_xor(se, off, 64);
        const float av = (e / se) * s_m[pb + pl];
        a[(size_t)(pbase + pb + pl)*64 + kc] = av;
        part += av;
    }
    atomicAdd(&sumA[b*64 + kc], part);
}

// ---------------------------------------------------------------------------
__global__ __launch_bounds__(256) void k_vlad_acc(
    const float* __restrict__ a, const float* __restrict__ f,
    float* __restrict__ vpart)
{
    __shared__ __align__(16) float s_a[32*64];
    __shared__ __align__(16) float s_f[32*128];
    const int b  = blockIdx.x >> 5;          // VCH=32
    const int ch = blockIdx.x & 31;
    const int n0 = ch * (N / VCH);
    const int tid = threadIdx.x;
    const int kc0 = (tid >> 5) * 8;
    const int d0  = (tid & 31) * 4;
    float acc[8][4];
    #pragma unroll
    for (int i = 0; i < 8; i++)
        #pragma unroll
        for (int j = 0; j < 4; j++) acc[i][j] = 0.f;
    for (int t = 0; t < N/VCH; t += 32) {
        __syncthreads();
        const size_t base = (size_t)(b*N + n0 + t);
        for (int i = tid; i < 32*64; i += 256)  s_a[i] = a[(base << 6) + i];
        for (int i = tid; i < 32*128; i += 256) s_f[i] = f[(base << 7) + i];
        __syncthreads();
        for (int n = 0; n < 32; n++) {
            const float4 a0 = *(const float4*)&s_a[n*64 + kc0];
            const float4 a1 = *(const float4*)&s_a[n*64 + kc0 + 4];
            const float4 fv = *(const float4*)&s_f[n*128 + d0];
            const float av[8] = {a0.x,a0.y,a0.z,a0.w,a1.x,a1.y,a1.z,a1.w};
            const float fw[4] = {fv.x,fv.y,fv.z,fv.w};
            #pragma unroll
            for (int i = 0; i < 8; i++)
                #pragma unroll
                for (int j = 0; j < 4; j++) acc[i][j] = fmaf(av[i], fw[j], acc[i][j]);
        }
    }
    float* vp = vpart + ((size_t)ch*B + b)*8192;
    #pragma unroll
    for (int i = 0; i < 8; i++)
        #pragma unroll
        for (int j = 0; j < 4; j++) vp[(kc0+i)*128 + d0 + j] = acc[i][j];
}

// ---------------------------------------------------------------------------
// Intra-normalize; also accumulates the per-batch global sum-of-squares
// (folds the old k_vnorm launch: sum over kc of tot/(s+eps)^2 == ||v_b||^2).
__global__ __launch_bounds__(128) void k_vlad_norm(
    const float* __restrict__ vpart, const float* __restrict__ sumA,
    const float* __restrict__ centers, float* __restrict__ v,
    float* __restrict__ ssq)
{
    const int b = blockIdx.x >> 6, kc = blockIdx.x & 63, d = threadIdx.x;
    float acc = 0.f;
    #pragma unroll
    for (int c = 0; c < VCH; c++)
        acc += vpart[((size_t)c*B + b)*8192 + kc*128 + d];
    const float vv = acc - sumA[b*64 + kc] * centers[kc*128 + d];
    float s2 = vv*vv;
    #pragma unroll
    for (int off = 32; off > 0; off >>= 1) s2 += __shfl_xor(s2, off, 64);
    __shared__ float red[2];
    if ((d & 63) == 0) red[d >> 6] = s2;
    __syncthreads();
    const float tot = red[0] + red[1];
    const float s = sqrtf(tot) + 1e-8f;
    v[((size_t)b*64 + kc)*128 + d] = vv / s;
    if (d == 0) atomicAdd(&ssq[b], tot / (s*s));
}

__global__ __launch_bounds__(256) void k_proj(
    const float* __restrict__ v, const float* __restrict__ ssq,
    const float* __restrict__ proj, float* __restrict__ outacc)
{
    __shared__ __align__(16) float s_v[8*256];
    __shared__ float s_sc[8];
    const int jc = blockIdx.x, o = threadIdx.x;
    const int j0 = jc * 256;
    for (int i = o; i < 8*256; i += 256) {
        const int bb = i >> 8, jj = i & 255;
        s_v[i] = v[(size_t)bb*8192 + j0 + jj];
    }
    if (o < 8) s_sc[o] = 1.f / (sqrtf(ssq[o]) + 1e-8f);
    __syncthreads();
    float acc[8] = {0.f,0.f,0.f,0.f,0.f,0.f,0.f,0.f};
    for (int jj = 0; jj < 256; jj += 4) {
        float pv[4];
        #pragma unroll
        for (int q = 0; q < 4; q++) pv[q] = proj[(size_t)(j0+jj+q)*256 + o];
        #pragma unroll
        for (int bb = 0; bb < 8; bb++) {
            const float4 vv = *(const float4*)&s_v[bb*256 + jj];
            acc[bb] = fmaf(vv.x, pv[0], acc[bb]);
            acc[bb] = fmaf(vv.y, pv[1], acc[bb]);
            acc[bb] = fmaf(vv.z, pv[2], acc[bb]);
            acc[bb] = fmaf(vv.w, pv[3], acc[bb]);
        }
    }
    #pragma unroll
    for (int bb = 0; bb < 8; bb++) atomicAdd(&outacc[bb*256 + o], acc[bb] * s_sc[bb]);
}

__global__ __launch_bounds__(256) void k_outnorm(
    const float* __restrict__ outacc, float* __restrict__ out)
{
    const int b = blockIdx.x, o = threadIdx.x;
    const float val = outacc[b*256 + o];
    float s = val*val;
    #pragma unroll
    for (int off = 32; off > 0; off >>= 1) s += __shfl_xor(s, off, 64);
    __shared__ float red[4];
    if ((o & 63) == 0) red[o >> 6] = s;
    __syncthreads();
    const float tot = red[0] + red[1] + red[2] + red[3];
    out[b*256 + o] = val / (sqrtf(tot) + 1e-12f);
}

// ---------------------------------------------------------------------------
extern "C" void kernel_launch(void* const* d_in, const int* in_sizes, int n_in,
                              void* d_out, int out_size, void* d_ws, size_t ws_size,
                              hipStream_t stream)
{
    (void)in_sizes; (void)n_in; (void)out_size; (void)ws_size;
    const float* x     = (const float*)d_in[0];
    const int*   m     = (const int*)  d_in[1];
    const float* pn_w1 = (const float*)d_in[2];
    const float* pn_b1 = (const float*)d_in[3];
    const float* pn_w2 = (const float*)d_in[4];
    const float* pn_b2 = (const float*)d_in[5];
    const float* kp    = (const float*)d_in[6];
    const float* bw1[3] = {(const float*)d_in[7],  (const float*)d_in[11], (const float*)d_in[15]};
    const float* bwk[3] = {(const float*)d_in[8],  (const float*)d_in[12], (const float*)d_in[16]};
    const float* bw2[3] = {(const float*)d_in[9],  (const float*)d_in[13], (const float*)d_in[17]};
    const float* bws[3] = {(const float*)d_in[10], (const float*)d_in[14], (const float*)d_in[18]};
    const float* vlad_wa      = (const float*)d_in[19];
    const float* vlad_centers = (const float*)d_in[20];
    const float* vlad_proj    = (const float*)d_in[21];
    float* out = (float*)d_out;

    char* ws = (char*)d_ws;
    size_t off = 0;
    auto alloc = [&](size_t bytes) -> void* {
        void* p = ws + off;
        off = (off + bytes + 255) & ~(size_t)255;
        return p;
    };
    float4* coords4 = (float4*)alloc((size_t)BN*16);
    float*  feat0   = (float*)alloc((size_t)BN*64*4);
    int*    idxb    = (int*)  alloc((size_t)BN*KNBR*4);
    unsigned short* x1A = (unsigned short*)alloc((size_t)BN*64*2);  // bf16 ping
    unsigned short* x1B = (unsigned short*)alloc((size_t)BN*64*2);  // bf16 pong
    float*  fA      = (float*)alloc((size_t)BN*128*4);
    float*  fB      = (float*)alloc((size_t)BN*128*4);
    float*  abuf    = (float*)alloc((size_t)BN*64*4);
    float*  vbuf    = (float*)alloc((size_t)B*8192*4);
    // contiguous zero region (k_prep tail): sumA | outacc | ssqb | cntb
    float*  sumA    = (float*)alloc((size_t)B*64*4);    // 2048 B (256-aligned)
    float*  outacc  = (float*)alloc((size_t)B*256*4);   // 8192 B
    float*  ssqb    = (float*)alloc((size_t)B*4);       // padded to 256 B
    int*    cntb    = (int*)  alloc((size_t)B*4);
    int*    compact = (int*)alloc((size_t)BN*4);
    short*  wkT[3]  = {(short*)alloc(64*960*2), (short*)alloc(64*960*2), (short*)alloc(64*960*2)};
    short*  catT[3] = {(short*)alloc(128*192*2), (short*)alloc(128*192*2), (short*)alloc(128*192*2)};
    short*  w1T1    = (short*)alloc(64*128*2);
    short*  w1T2    = (short*)alloc(64*128*2);
    float*  vpart   = fB;   // fB dead after layer-2 reads it; 8 MB fits VCH=32 exactly

    k_prep<<<(3*61440 + 81920 + ZERON + 255)/256, 256, 0, stream>>>(
        bwk[0], bwk[1], bwk[2], bw2[0], bws[0], bw2[1], bws[1], bw2[2], bws[2],
        bw1[1], bw1[2],
        wkT[0], wkT[1], wkT[2], catT[0], catT[1], catT[2], w1T1, w1T2, sumA);

    k_compact<<<BN/256, 256, 0, stream>>>(m, compact, cntb, idxb);
    k_pointnet<<<BN/32, 256, 0, stream>>>(x, m, pn_w1, pn_b1, pn_w2, pn_b2, bw1[0],
                                          feat0, coords4, x1A);
    k_knn<<<B*512, 256, 0, stream>>>(coords4, compact, cntb, idxb);

    k_kpconv<64,true>  <<<BN/16, 512, 0, stream>>>(x1A, coords4, kp, idxb, feat0, wkT[0], catT[0], w1T1, x1B, fA);
    k_kpconv<128,true> <<<BN/16, 512, 0, stream>>>(x1B, coords4, kp, idxb, fA,    wkT[1], catT[1], w1T2, x1A, fB);
    k_kpconv<128,false><<<BN/16, 512, 0, stream>>>(x1A, coords4, kp, idxb, fB,    wkT[2], catT[2], nullptr, nullptr, fA);

    k_vlad_a<<<BN/32, 256, 0, stream>>>(fA, vlad_wa, m, abuf, sumA);
    k_vlad_acc<<<B*VCH, 256, 0, stream>>>(abuf, fA, vpart);
    k_vlad_norm<<<B*64, 128, 0, stream>>>(vpart, sumA, vlad_centers, vbuf, ssqb);
    k_proj<<<32, 256, 0, stream>>>(vbuf, ssqb, vlad_proj, outacc);
    k_outnorm<<<B, 256, 0, stream>>>(outacc, out);
}

// Round 5
// 362.831 us; speedup vs baseline: 1.0026x; 1.0026x over previous
//
#include <hip/hip_runtime.h>
#include <hip/hip_bf16.h>

#define B 8
#define N 2048
#define BN (B*N)
#define KNBR 32
#define NKP 15
#define VCH 32   // n-chunks per batch in VLAD accumulation (32 -> 256 blocks)

#define ZERON 2632   // floats zeroed by k_prep tail: sumA(512)+outacc(2048)+ssq(64 pad)+cnt(8)

__device__ __forceinline__ float lrelu(float x){ return x > 0.f ? x : 0.1f*x; }
__device__ __forceinline__ unsigned umin_(unsigned a, unsigned b){ return __builtin_elementwise_min(a, b); }
__device__ __forceinline__ unsigned umax_(unsigned a, unsigned b){ return __builtin_elementwise_max(a, b); }

// MFMA fragment types (per guide: short8 = 8 bf16 = 4 VGPRs)
typedef __attribute__((ext_vector_type(8))) short bf16x8;
typedef __attribute__((ext_vector_type(4))) float fx4;

__device__ __forceinline__ short bfr(float f){
    union { __hip_bfloat16 h; short s; } u;
    u.h = __float2bfloat16(f);
    return u.s;
}
__device__ __forceinline__ unsigned pk2(float a, float b){
    return ((unsigned)(unsigned short)bfr(b) << 16) | (unsigned)(unsigned short)bfr(a);
}

// ---------------------------------------------------------------------------
// Fused weight prep: 3x wkT + 3x catT + 2x w1T, plus workspace zeroing tail
// (absorbs the old k_zero launch; zbuf spans sumA|outacc|ssq|cnt contiguously).
__global__ __launch_bounds__(256) void k_prep(
    const float* __restrict__ wk0, const float* __restrict__ wk1, const float* __restrict__ wk2,
    const float* __restrict__ w20, const float* __restrict__ ws0,
    const float* __restrict__ w21, const float* __restrict__ ws1,
    const float* __restrict__ w22, const float* __restrict__ ws2,
    const float* __restrict__ w1_1, const float* __restrict__ w1_2,
    short* __restrict__ wkT0, short* __restrict__ wkT1, short* __restrict__ wkT2,
    short* __restrict__ cat0, short* __restrict__ cat1, short* __restrict__ cat2,
    short* __restrict__ w1T1, short* __restrict__ w1T2,
    float* __restrict__ zbuf)
{
    const int i = blockIdx.x * 256 + threadIdx.x;
    if (i < 3*61440) {
        const int l = i / 61440, r = i % 61440;
        const int n = r / 960, k = r % 960;
        const float* wk = (l == 0) ? wk0 : (l == 1) ? wk1 : wk2;
        short* dst = (l == 0) ? wkT0 : (l == 1) ? wkT1 : wkT2;
        dst[r] = bfr(wk[k*64 + n]);
    } else {
        int j = i - 3*61440;
        if (j < 16384) {
            const int n = j / 128, k = j % 128;
            cat0[j] = bfr(k < 64 ? w20[k*128 + n] : ws0[(k-64)*128 + n]);
        } else if (j < 16384 + 24576) {
            j -= 16384;
            const int n = j / 192, k = j % 192;
            cat1[j] = bfr(k < 64 ? w21[k*128 + n] : ws1[(k-64)*128 + n]);
        } else if (j < 16384 + 49152) {
            j -= 16384 + 24576;
            const int n = j / 192, k = j % 192;
            cat2[j] = bfr(k < 64 ? w22[k*128 + n] : ws2[(k-64)*128 + n]);
        } else if (j < 16384 + 49152 + 8192) {
            j -= 16384 + 49152;
            const int n = j / 128, k = j % 128;
            w1T1[j] = bfr(w1_1[k*64 + n]);
        } else if (j < 16384 + 49152 + 16384) {
            j -= 16384 + 49152 + 8192;
            const int n = j / 128, k = j % 128;
            w1T2[j] = bfr(w1_2[k*64 + n]);
        } else {
            const int z = j - (16384 + 49152 + 16384);
            if (z < ZERON) zbuf[z] = 0.f;
        }
    }
}

// ---------------------------------------------------------------------------
// Compaction with wave-aggregated atomics (round-10 verified).
__global__ __launch_bounds__(256) void k_compact(
    const int* __restrict__ m, int* __restrict__ compact, int* __restrict__ cnt,
    int* __restrict__ idx)
{
    const int p = blockIdx.x * 256 + threadIdx.x;
    const int b = p >> 11, n = p & (N-1);
    const int lane = threadIdx.x & 63;
    const bool unm = (m[p] == 0);
    const unsigned long long mask = __ballot(unm);
    int base = 0;
    if (lane == 0) base = atomicAdd(&cnt[b], __popcll(mask));
    base = __shfl(base, 0, 64);
    if (unm) {
        const int pos = base + __popcll(mask & ((1ull << lane) - 1ull));
        compact[b*N + pos] = n;
    } else {
        #pragma unroll
        for (int k = 0; k < KNBR; k++) idx[(size_t)p*KNBR + k] = k;
    }
}

// ---------------------------------------------------------------------------
// PointNet + FUSED layer-0 unary (x1 = lrelu(feat@W1)), bf16 x1 out.
__global__ __launch_bounds__(256) void k_pointnet(
    const float* __restrict__ x, const int* __restrict__ m,
    const float* __restrict__ w1, const float* __restrict__ b1,
    const float* __restrict__ w2, const float* __restrict__ b2,
    const float* __restrict__ wu,
    float* __restrict__ feat, float4* __restrict__ coords4,
    unsigned short* __restrict__ x1out)
{
    __shared__ float s_x[32][3];
    __shared__ __align__(16) float s_hT[64*40];
    __shared__ __align__(16) float s_fT[64*40];
    const int tid = threadIdx.x;
    const int pbase = blockIdx.x * 32;
    if (tid < 32) {
        const int p = pbase + tid;
        const float x0 = x[p*3+0], x1v = x[p*3+1], x2v = x[p*3+2];
        s_x[tid][0] = x0; s_x[tid][1] = x1v; s_x[tid][2] = x2v;
        const bool mm = (m[p] != 0);
        const float cx = mm ? 1e6f : x0, cy = mm ? 1e6f : x1v, cz = mm ? 1e6f : x2v;
        coords4[p] = make_float4(cx, cy, cz, cx*cx + cy*cy + cz*cz);
    }
    __syncthreads();
    const int w = tid >> 6, c = tid & 63;
    const int pb = w * 8;
    {
        const float w10 = w1[c], w11 = w1[64+c], w12 = w1[128+c], bb = b1[c];
        #pragma unroll
        for (int pl = 0; pl < 8; pl++) {
            float s = bb;
            s = fmaf(s_x[pb+pl][0], w10, s);
            s = fmaf(s_x[pb+pl][1], w11, s);
            s = fmaf(s_x[pb+pl][2], w12, s);
            s_hT[c*40 + pb + pl] = fmaxf(s, 0.f);
        }
    }
    {
        float acc[8];
        const float bb = b2[c];
        #pragma unroll
        for (int pl = 0; pl < 8; pl++) acc[pl] = bb;
        for (int j = 0; j < 64; j++) {
            const float wv = w2[j*64 + c];
            const float4 h0 = *(const float4*)&s_hT[j*40 + pb];
            const float4 h1 = *(const float4*)&s_hT[j*40 + pb + 4];
            acc[0] = fmaf(h0.x, wv, acc[0]); acc[1] = fmaf(h0.y, wv, acc[1]);
            acc[2] = fmaf(h0.z, wv, acc[2]); acc[3] = fmaf(h0.w, wv, acc[3]);
            acc[4] = fmaf(h1.x, wv, acc[4]); acc[5] = fmaf(h1.y, wv, acc[5]);
            acc[6] = fmaf(h1.z, wv, acc[6]); acc[7] = fmaf(h1.w, wv, acc[7]);
        }
        #pragma unroll
        for (int pl = 0; pl < 8; pl++) {
            const float fv = fmaxf(acc[pl], 0.f);
            feat[(size_t)(pbase + pb + pl)*64 + c] = fv;
            s_fT[c*40 + pb + pl] = fv;
        }
    }
    __syncthreads();
    // stage 3: x1 = lrelu(feat @ wu), bf16 out
    {
        float acc[8] = {0.f,0.f,0.f,0.f,0.f,0.f,0.f,0.f};
        for (int j = 0; j < 64; j++) {
            const float wv = wu[j*64 + c];
            const float4 f0 = *(const float4*)&s_fT[j*40 + pb];
            const float4 f1 = *(const float4*)&s_fT[j*40 + pb + 4];
            acc[0] = fmaf(f0.x, wv, acc[0]); acc[1] = fmaf(f0.y, wv, acc[1]);
            acc[2] = fmaf(f0.z, wv, acc[2]); acc[3] = fmaf(f0.w, wv, acc[3]);
            acc[4] = fmaf(f1.x, wv, acc[4]); acc[5] = fmaf(f1.y, wv, acc[5]);
            acc[6] = fmaf(f1.z, wv, acc[6]); acc[7] = fmaf(f1.w, wv, acc[7]);
        }
        #pragma unroll
        for (int pl = 0; pl < 8; pl++)
            x1out[(size_t)(pbase + pb + pl)*64 + c] = (unsigned short)bfr(lrelu(acc[pl]));
    }
}

// ---------------------------------------------------------------------------
// KNN — round-4 occupancy fix: 512 threads (8 queries/block, was 4).
// Measured (round-4): 68.6 µs, VALUBusy 68%, Occupancy 31% (2.5 waves/SIMD) —
// latency-bound on shuffle/sort dep-chains with too few resident waves.
// 8 waves x 32KB LDS -> 4 blocks/CU = 32 waves/CU (100% theoretical);
// ~1024 active blocks = exactly one resident generation on 256 CUs.
// Per-wave algorithm, packing, and tie-breaking are UNCHANGED -> bit-identical idx.
__global__ __launch_bounds__(512, 8) void k_knn(
    const float4* __restrict__ c4, const int* __restrict__ compact,
    const int* __restrict__ cnt, int* __restrict__ idx)
{
    const int b = blockIdx.x >> 8;
    const int slot0 = (blockIdx.x & 255) * 8;
    const int cn = cnt[b];
    if (slot0 >= cn) return;
    __shared__ float4 s_c[N];
    const int tid = threadIdx.x;
    const int w = tid >> 6, lane = tid & 63;
    for (int i = tid; i < N; i += 512) s_c[i] = c4[(size_t)b*N + i];
    __syncthreads();
    const int slot = slot0 + w;
    const bool active = slot < cn;
    const int n = active ? compact[b*N + slot] : 0;
    const float4 me = s_c[n];

    unsigned A[32];
    #pragma unroll
    for (int j = 0; j < 32; j++) {
        const float4 s = s_c[j*64 + lane];
        float d2 = me.w + s.w - 2.f*(me.x*s.x + me.y*s.y + me.z*s.z);
        d2 = fmaxf(d2, 0.f);
        A[j] = (__float_as_uint(d2) & 0xFFFFF800u) | (unsigned)(j*64 + lane);
    }
    #pragma unroll
    for (int k = 2; k <= 32; k <<= 1) {
        #pragma unroll
        for (int j = k >> 1; j > 0; j >>= 1) {
            #pragma unroll
            for (int i = 0; i < 32; i++) {
                const int l = i ^ j;
                if (l > i) {
                    const unsigned lo = umin_(A[i], A[l]);
                    const unsigned hi = umax_(A[i], A[l]);
                    const bool up = ((i & k) == 0);
                    A[i] = up ? lo : hi;
                    A[l] = up ? hi : lo;
                }
            }
        }
    }
    #pragma unroll
    for (int r = 0; r < 6; r++) {
        const int mask = 1 << r;
        #pragma unroll
        for (int i = 0; i < 16; i++) {
            const unsigned t1 = (unsigned)__shfl_xor((int)A[31-i], mask, 64);
            const unsigned t2 = (unsigned)__shfl_xor((int)A[i],    mask, 64);
            A[i]    = umin_(A[i],    t1);
            A[31-i] = umin_(A[31-i], t2);
        }
        if (r < 5) {
            #pragma unroll
            for (int j = 16; j > 0; j >>= 1) {
                #pragma unroll
                for (int i = 0; i < 32; i++) {
                    const int l = i ^ j;
                    if (l > i) {
                        const unsigned lo = umin_(A[i], A[l]);
                        A[l] = umax_(A[i], A[l]);
                        A[i] = lo;
                    }
                }
            }
        }
    }
    #pragma unroll
    for (int s = 16; s >= 1; s >>= 1) {
        #pragma unroll
        for (int i = 0; i < s; i++)
            A[i] = (lane & s) ? A[i+s] : A[i];
    }
    if (active && lane < 32)
        idx[(size_t)(b*N + n)*KNBR + lane] = (int)(A[0] & 0x7FFu);
}

// ---------------------------------------------------------------------------
// KPConv, 16 pts/block, 512 threads, all-MFMA, bf16 x1 gather, fused phase 4.
template<int CIN, bool FUSE>
__global__ __launch_bounds__(512) void k_kpconv(
    const unsigned short* __restrict__ x1, const float4* __restrict__ c4,
    const float* __restrict__ kp,
    const int* __restrict__ idx, const float* __restrict__ feat_in,
    const short* __restrict__ WkT, const short* __restrict__ WcatT,
    const short* __restrict__ W1T, unsigned short* __restrict__ x1out,
    float* __restrict__ out)
{
    constexpr int KC = 64 + CIN;   // phase-3 K extent
    constexpr int AS = 976;        // aggT row stride (shorts)
    constexpr int XS = 72;         // x2 row stride (shorts)
    constexpr int FS = CIN + 8;    // feat row stride (shorts)
    constexpr int PS = 65;         // partial row stride (floats)
    constexpr int FOS = 136;       // fused fout row stride (shorts)
    __shared__ __align__(16) short s_aggT[16*AS];      // 31232 B
    __shared__ __align__(16) unsigned s_un[11264];     // 45056 B union region
    __shared__ int   s_idx[512];
    __shared__ float skp[48];

    const int tid   = threadIdx.x;
    const int pbase = blockIdx.x * 16;
    const int brow  = pbase & ~(N-1);
    const int w = tid >> 6, lane = tid & 63;

    if (tid < NKP*3) skp[tid] = kp[tid];
    s_idx[tid] = idx[(size_t)pbase*KNBR + tid];
    __syncthreads();

    // ---- phase 1: wave w -> points 2w, 2w+1 (per-wave, no barriers) ----
    unsigned* xg  = s_un + w*1408;                    // [64 ch][18 dwords]
    short*    wbf = (short*)(s_un + w*1408 + 1152);   // [16 kp][32 nbr]

    for (int sub = 0; sub < 2; sub++) {
        const int pl = w*2 + sub;
        {
            const int k = lane & 31, h = lane >> 5;
            const float4 cp = c4[pbase + pl];
            const float4 cn = c4[brow + s_idx[pl*KNBR + k]];
            const float dx = cn.x - cp.x, dy = cn.y - cp.y, dz = cn.z - cp.z;
            #pragma unroll
            for (int j = 0; j < 8; j++) {
                const int kpi = h*8 + j;
                if (kpi < NKP) {
                    const float ex = dx - skp[kpi*3], ey = dy - skp[kpi*3+1], ez = dz - skp[kpi*3+2];
                    const float dist = sqrtf(ex*ex + ey*ey + ez*ez);
                    wbf[kpi*32 + k] = bfr(fmaxf(0.f, 1.f - dist*2.f));
                }
            }
        }
        {
            unsigned short g[KNBR];
            #pragma unroll
            for (int k = 0; k < KNBR; k++)
                g[k] = x1[(size_t)(brow + s_idx[pl*KNBR + k])*64 + lane];
            #pragma unroll
            for (int i = 0; i < 16; i++)
                xg[lane*18 + i] = (unsigned)g[2*i] | ((unsigned)g[2*i+1] << 16);
        }
        {
            const int n = lane & 15, q = lane >> 4;
            const bf16x8 bw = *(const bf16x8*)&wbf[n*32 + q*8];
            #pragma unroll
            for (int t = 0; t < 4; t++) {
                union { unsigned u[4]; bf16x8 v; } af;
                const unsigned* src = &xg[(t*16 + n)*18 + q*4];
                af.u[0] = src[0]; af.u[1] = src[1]; af.u[2] = src[2]; af.u[3] = src[3];
                fx4 d = {0.f,0.f,0.f,0.f};
                d = __builtin_amdgcn_mfma_f32_16x16x32_bf16(af.v, bw, d, 0, 0, 0);
                if (n < NKP) {
                    const uint2 o = make_uint2(pk2(d[0], d[1]), pk2(d[2], d[3]));
                    *(uint2*)&s_aggT[pl*AS + n*64 + t*16 + q*4] = o;
                }
            }
        }
    }
    __syncthreads();   // phase-1 region dead; union re-partitioned:

    short* s_x2bf   = (short*)s_un;                        // [16][XS]
    short* s_featbf = (short*)s_un + 16*XS;                // [16][FS]
    float* s_part   = (float*)((char*)s_un + 6656);        // [2][16][PS]

    for (int i = tid; i < 16*CIN; i += 512) {
        const int p = i / CIN, j = i % CIN;
        s_featbf[p*FS + j] = bfr(feat_in[(size_t)pbase*CIN + i]);
    }

    const int nlane = lane & 15, q = lane >> 4;
    // phase 2: x2 = lrelu(agg @ Wk). wave w -> col-tile (w&3), K-half (w>>2).
    {
        const int ct = w & 3, kh = w >> 2;
        fx4 acc = {0.f,0.f,0.f,0.f};
        const short* arow = &s_aggT[nlane*AS + kh*480];
        const short* brw  = &WkT[(size_t)(ct*16 + nlane)*960 + kh*480];
        for (int t = 0; t < 15; t++) {
            const int k0 = t*32 + q*8;
            const bf16x8 af = *(const bf16x8*)&arow[k0];
            const bf16x8 bf = *(const bf16x8*)&brw[k0];
            acc = __builtin_amdgcn_mfma_f32_16x16x32_bf16(af, bf, acc, 0, 0, 0);
        }
        float* pp = s_part + kh*(16*PS);
        #pragma unroll
        for (int r = 0; r < 4; r++)
            pp[(q*4+r)*PS + ct*16 + nlane] = acc[r];
    }
    __syncthreads();
    for (int i = tid; i < 1024; i += 512) {
        const int pt = i >> 6, c = i & 63;
        const float v = s_part[pt*PS + c] + s_part[16*PS + pt*PS + c];
        s_x2bf[pt*XS + c] = bfr(lrelu(v));
    }
    __syncthreads();

    // phase 3: out = lrelu([x2|feat] @ [W2;Ws]). wave w -> cols [16w,16w+16).
    fx4 acc0 = {0.f,0.f,0.f,0.f};
    {
        const short* b0r = &WcatT[(size_t)(w*16 + nlane)*KC];
        const short* xrow = &s_x2bf[nlane*XS];
        const short* frow = &s_featbf[nlane*FS];
        #pragma unroll
        for (int t = 0; t < KC/32; t++) {
            const int k0 = t*32 + q*8;
            const short* src = (t < 2) ? &xrow[k0] : &frow[k0 - 64];
            const bf16x8 af = *(const bf16x8*)src;
            const bf16x8 b0 = *(const bf16x8*)&b0r[k0];
            acc0 = __builtin_amdgcn_mfma_f32_16x16x32_bf16(af, b0, acc0, 0, 0, 0);
        }
        #pragma unroll
        for (int r = 0; r < 4; r++)
            out[(size_t)(pbase + q*4 + r)*128 + w*16 + nlane] = lrelu(acc0[r]);
    }

    if (FUSE) {
        // phase 4: x1out = lrelu(out @ W1) for the NEXT layer, in-block.
        __syncthreads();   // all phase-3 LDS reads done; re-alias s_un
        short* s_fout = (short*)s_un;   // [16][FOS]
        #pragma unroll
        for (int r = 0; r < 4; r++)
            s_fout[(q*4 + r)*FOS + w*16 + nlane] = bfr(lrelu(acc0[r]));
        __syncthreads();
        if (w < 4) {
            fx4 acc = {0.f,0.f,0.f,0.f};
            const short* arow = &s_fout[nlane*FOS];
            const short* brw  = &W1T[(size_t)(w*16 + nlane)*128];
            #pragma unroll
            for (int t = 0; t < 4; t++) {
                const int k0 = t*32 + q*8;
                const bf16x8 af = *(const bf16x8*)&arow[k0];
                const bf16x8 bf = *(const bf16x8*)&brw[k0];
                acc = __builtin_amdgcn_mfma_f32_16x16x32_bf16(af, bf, acc, 0, 0, 0);
            }
            #pragma unroll
            for (int r = 0; r < 4; r++)
                x1out[(size_t)(pbase + q*4 + r)*64 + w*16 + nlane] =
                    (unsigned short)bfr(lrelu(acc[r]));
        }
    }
}

// ---------------------------------------------------------------------------
__global__ __launch_bounds__(256) void k_vlad_a(
    const float* __restrict__ f, const float* __restrict__ wa,
    const int* __restrict__ m, float* __restrict__ a, float* __restrict__ sumA)
{
    __shared__ __align__(16) float s_fT[128*36 + 8];
    __shared__ float s_m[32];
    const int tid = threadIdx.x;
    const int pbase = blockIdx.x * 32;
    const int b = pbase >> 11;
    for (int i = tid; i < 32*128; i += 256) {
        const int p = i >> 7, j = i & 127;
        s_fT[j*36 + p] = f[(size_t)pbase*128 + i];
    }
    if (tid < 32) s_m[tid] = (m[pbase + tid] != 0) ? 0.f : 1.f;
    __syncthreads();
    const int w = tid >> 6, kc = tid & 63;
    const int pb = w * 8;
    float acc[8] = {0.f,0.f,0.f,0.f,0.f,0.f,0.f,0.f};
    for (int j = 0; j < 128; j++) {
        const float wv = wa[j*64 + kc];
        const float4 f0 = *(const float4*)&s_fT[j*36 + pb];
        const float4 f1 = *(const float4*)&s_fT[j*36 + pb + 4];
        acc[0] = fmaf(f0.x, wv, acc[0]); acc[1] = fmaf(f0.y, wv, acc[1]);
        acc[2] = fmaf(f0.z, wv, acc[2]); acc[3] = fmaf(f0.w, wv, acc[3]);
        acc[4] = fmaf(f1.x, wv, acc[4]); acc[5] = fmaf(f1.y, wv, acc[5]);
        acc[6] = fmaf(f1.z, wv, acc[6]); acc[7] = fmaf(f1.w, wv, acc[7]);
    }
    float part = 0.f;
    #pragma unroll
    for (int pl = 0; pl < 8; pl++) {
        float mx = acc[pl];
        #pragma unroll
        for (int off = 32; off > 0; off >>= 1) mx = fmaxf(mx, __shfl_xor(mx, off, 64));
        const float e = expf(acc[pl] - mx);
        float se = e;
        #pragma unroll
        for (int off = 32; off > 0; off >>= 1) se += __shfl_xor(se, off, 64);
        const float av = (e / se) * s_m[pb + pl];
        a[(size_t)(pbase + pb + pl)*64 + kc] = av;
        part += av;
    }
    atomicAdd(&sumA[b*64 + kc], part);
}

// ---------------------------------------------------------------------------
__global__ __launch_bounds__(256) void k_vlad_acc(
    const float* __restrict__ a, const float* __restrict__ f,
    float* __restrict__ vpart)
{
    __shared__ __align__(16) float s_a[32*64];
    __shared__ __align__(16) float s_f[32*128];
    const int b  = blockIdx.x >> 5;          // VCH=32
    const int ch = blockIdx.x & 31;
    const int n0 = ch * (N / VCH);
    const int tid = threadIdx.x;
    const int kc0 = (tid >> 5) * 8;
    const int d0  = (tid & 31) * 4;
    float acc[8][4];
    #pragma unroll
    for (int i = 0; i < 8; i++)
        #pragma unroll
        for (int j = 0; j < 4; j++) acc[i][j] = 0.f;
    for (int t = 0; t < N/VCH; t += 32) {
        __syncthreads();
        const size_t base = (size_t)(b*N + n0 + t);
        for (int i = tid; i < 32*64; i += 256)  s_a[i] = a[(base << 6) + i];
        for (int i = tid; i < 32*128; i += 256) s_f[i] = f[(base << 7) + i];
        __syncthreads();
        for (int n = 0; n < 32; n++) {
            const float4 a0 = *(const float4*)&s_a[n*64 + kc0];
            const float4 a1 = *(const float4*)&s_a[n*64 + kc0 + 4];
            const float4 fv = *(const float4*)&s_f[n*128 + d0];
            const float av[8] = {a0.x,a0.y,a0.z,a0.w,a1.x,a1.y,a1.z,a1.w};
            const float fw[4] = {fv.x,fv.y,fv.z,fv.w};
            #pragma unroll
            for (int i = 0; i < 8; i++)
                #pragma unroll
                for (int j = 0; j < 4; j++) acc[i][j] = fmaf(av[i], fw[j], acc[i][j]);
        }
    }
    float* vp = vpart + ((size_t)ch*B + b)*8192;
    #pragma unroll
    for (int i = 0; i < 8; i++)
        #pragma unroll
        for (int j = 0; j < 4; j++) vp[(kc0+i)*128 + d0 + j] = acc[i][j];
}

// ---------------------------------------------------------------------------
// Intra-normalize; also accumulates the per-batch global sum-of-squares
// (folds the old k_vnorm launch: sum over kc of tot/(s+eps)^2 == ||v_b||^2).
__global__ __launch_bounds__(128) void k_vlad_norm(
    const float* __restrict__ vpart, const float* __restrict__ sumA,
    const float* __restrict__ centers, float* __restrict__ v,
    float* __restrict__ ssq)
{
    const int b = blockIdx.x >> 6, kc = blockIdx.x & 63, d = threadIdx.x;
    float acc = 0.f;
    #pragma unroll
    for (int c = 0; c < VCH; c++)
        acc += vpart[((size_t)c*B + b)*8192 + kc*128 + d];
    const float vv = acc - sumA[b*64 + kc] * centers[kc*128 + d];
    float s2 = vv*vv;
    #pragma unroll
    for (int off = 32; off > 0; off >>= 1) s2 += __shfl_xor(s2, off, 64);
    __shared__ float red[2];
    if ((d & 63) == 0) red[d >> 6] = s2;
    __syncthreads();
    const float tot = red[0] + red[1];
    const float s = sqrtf(tot) + 1e-8f;
    v[((size_t)b*64 + kc)*128 + d] = vv / s;
    if (d == 0) atomicAdd(&ssq[b], tot / (s*s));
}

__global__ __launch_bounds__(256) void k_proj(
    const float* __restrict__ v, const float* __restrict__ ssq,
    const float* __restrict__ proj, float* __restrict__ outacc)
{
    __shared__ __align__(16) float s_v[8*256];
    __shared__ float s_sc[8];
    const int jc = blockIdx.x, o = threadIdx.x;
    const int j0 = jc * 256;
    for (int i = o; i < 8*256; i += 256) {
        const int bb = i >> 8, jj = i & 255;
        s_v[i] = v[(size_t)bb*8192 + j0 + jj];
    }
    if (o < 8) s_sc[o] = 1.f / (sqrtf(ssq[o]) + 1e-8f);
    __syncthreads();
    float acc[8] = {0.f,0.f,0.f,0.f,0.f,0.f,0.f,0.f};
    for (int jj = 0; jj < 256; jj += 4) {
        float pv[4];
        #pragma unroll
        for (int q = 0; q < 4; q++) pv[q] = proj[(size_t)(j0+jj+q)*256 + o];
        #pragma unroll
        for (int bb = 0; bb < 8; bb++) {
            const float4 vv = *(const float4*)&s_v[bb*256 + jj];
            acc[bb] = fmaf(vv.x, pv[0], acc[bb]);
            acc[bb] = fmaf(vv.y, pv[1], acc[bb]);
            acc[bb] = fmaf(vv.z, pv[2], acc[bb]);
            acc[bb] = fmaf(vv.w, pv[3], acc[bb]);
        }
    }
    #pragma unroll
    for (int bb = 0; bb < 8; bb++) atomicAdd(&outacc[bb*256 + o], acc[bb] * s_sc[bb]);
}

__global__ __launch_bounds__(256) void k_outnorm(
    const float* __restrict__ outacc, float* __restrict__ out)
{
    const int b = blockIdx.x, o = threadIdx.x;
    const float val = outacc[b*256 + o];
    float s = val*val;
    #pragma unroll
    for (int off = 32; off > 0; off >>= 1) s += __shfl_xor(s, off, 64);
    __shared__ float red[4];
    if ((o & 63) == 0) red[o >> 6] = s;
    __syncthreads();
    const float tot = red[0] + red[1] + red[2] + red[3];
    out[b*256 + o] = val / (sqrtf(tot) + 1e-12f);
}

// ---------------------------------------------------------------------------
extern "C" void kernel_launch(void* const* d_in, const int* in_sizes, int n_in,
                              void* d_out, int out_size, void* d_ws, size_t ws_size,
                              hipStream_t stream)
{
    (void)in_sizes; (void)n_in; (void)out_size; (void)ws_size;
    const float* x     = (const float*)d_in[0];
    const int*   m     = (const int*)  d_in[1];
    const float* pn_w1 = (const float*)d_in[2];
    const float* pn_b1 = (const float*)d_in[3];
    const float* pn_w2 = (const float*)d_in[4];
    const float* pn_b2 = (const float*)d_in[5];
    const float* kp    = (const float*)d_in[6];
    const float* bw1[3] = {(const float*)d_in[7],  (const float*)d_in[11], (const float*)d_in[15]};
    const float* bwk[3] = {(const float*)d_in[8],  (const float*)d_in[12], (const float*)d_in[16]};
    const float* bw2[3] = {(const float*)d_in[9],  (const float*)d_in[13], (const float*)d_in[17]};
    const float* bws[3] = {(const float*)d_in[10], (const float*)d_in[14], (const float*)d_in[18]};
    const float* vlad_wa      = (const float*)d_in[19];
    const float* vlad_centers = (const float*)d_in[20];
    const float* vlad_proj    = (const float*)d_in[21];
    float* out = (float*)d_out;

    char* ws = (char*)d_ws;
    size_t off = 0;
    auto alloc = [&](size_t bytes) -> void* {
        void* p = ws + off;
        off = (off + bytes + 255) & ~(size_t)255;
        return p;
    };
    float4* coords4 = (float4*)alloc((size_t)BN*16);
    float*  feat0   = (float*)alloc((size_t)BN*64*4);
    int*    idxb    = (int*)  alloc((size_t)BN*KNBR*4);
    unsigned short* x1A = (unsigned short*)alloc((size_t)BN*64*2);  // bf16 ping
    unsigned short* x1B = (unsigned short*)alloc((size_t)BN*64*2);  // bf16 pong
    float*  fA      = (float*)alloc((size_t)BN*128*4);
    float*  fB      = (float*)alloc((size_t)BN*128*4);
    float*  abuf    = (float*)alloc((size_t)BN*64*4);
    float*  vbuf    = (float*)alloc((size_t)B*8192*4);
    // contiguous zero region (k_prep tail): sumA | outacc | ssqb | cntb
    float*  sumA    = (float*)alloc((size_t)B*64*4);    // 2048 B (256-aligned)
    float*  outacc  = (float*)alloc((size_t)B*256*4);   // 8192 B
    float*  ssqb    = (float*)alloc((size_t)B*4);       // padded to 256 B
    int*    cntb    = (int*)  alloc((size_t)B*4);
    int*    compact = (int*)alloc((size_t)BN*4);
    short*  wkT[3]  = {(short*)alloc(64*960*2), (short*)alloc(64*960*2), (short*)alloc(64*960*2)};
    short*  catT[3] = {(short*)alloc(128*192*2), (short*)alloc(128*192*2), (short*)alloc(128*192*2)};
    short*  w1T1    = (short*)alloc(64*128*2);
    short*  w1T2    = (short*)alloc(64*128*2);
    float*  vpart   = fB;   // fB dead after layer-2 reads it; 8 MB fits VCH=32 exactly

    k_prep<<<(3*61440 + 81920 + ZERON + 255)/256, 256, 0, stream>>>(
        bwk[0], bwk[1], bwk[2], bw2[0], bws[0], bw2[1], bws[1], bw2[2], bws[2],
        bw1[1], bw1[2],
        wkT[0], wkT[1], wkT[2], catT[0], catT[1], catT[2], w1T1, w1T2, sumA);

    k_compact<<<BN/256, 256, 0, stream>>>(m, compact, cntb, idxb);
    k_pointnet<<<BN/32, 256, 0, stream>>>(x, m, pn_w1, pn_b1, pn_w2, pn_b2, bw1[0],
                                          feat0, coords4, x1A);
    k_knn<<<B*256, 512, 0, stream>>>(coords4, compact, cntb, idxb);

    k_kpconv<64,true>  <<<BN/16, 512, 0, stream>>>(x1A, coords4, kp, idxb, feat0, wkT[0], catT[0], w1T1, x1B, fA);
    k_kpconv<128,true> <<<BN/16, 512, 0, stream>>>(x1B, coords4, kp, idxb, fA,    wkT[1], catT[1], w1T2, x1A, fB);
    k_kpconv<128,false><<<BN/16, 512, 0, stream>>>(x1A, coords4, kp, idxb, fB,    wkT[2], catT[2], nullptr, nullptr, fA);

    k_vlad_a<<<BN/32, 256, 0, stream>>>(fA, vlad_wa, m, abuf, sumA);
    k_vlad_acc<<<B*VCH, 256, 0, stream>>>(abuf, fA, vpart);
    k_vlad_norm<<<B*64, 128, 0, stream>>>(vpart, sumA, vlad_centers, vbuf, ssqb);
    k_proj<<<32, 256, 0, stream>>>(vbuf, ssqb, vlad_proj, outacc);
    k_outnorm<<<B, 256, 0, stream>>>(outacc, out);
}

// Round 7
// 315.776 us; speedup vs baseline: 1.1520x; 1.1490x over previous
//
#include <hip/hip_runtime.h>
#include <hip/hip_bf16.h>

#define B 8
#define N 2048
#define BN (B*N)
#define KNBR 32
#define NKP 15
#define VCH 32   // n-chunks per batch in VLAD accumulation (32 -> 256 blocks)

#define ZERON 2632   // floats zeroed by k_prep tail: sumA(512)+outacc(2048)+ssq(64 pad)+cnt(8)

__device__ __forceinline__ float lrelu(float x){ return x > 0.f ? x : 0.1f*x; }
__device__ __forceinline__ unsigned umin_(unsigned a, unsigned b){ return __builtin_elementwise_min(a, b); }
__device__ __forceinline__ unsigned umax_(unsigned a, unsigned b){ return __builtin_elementwise_max(a, b); }

// MFMA fragment types (per guide: short8 = 8 bf16 = 4 VGPRs)
typedef __attribute__((ext_vector_type(8))) short bf16x8;
typedef __attribute__((ext_vector_type(4))) float fx4;

__device__ __forceinline__ short bfr(float f){
    union { __hip_bfloat16 h; short s; } u;
    u.h = __float2bfloat16(f);
    return u.s;
}
__device__ __forceinline__ unsigned pk2(float a, float b){
    return ((unsigned)(unsigned short)bfr(b) << 16) | (unsigned)(unsigned short)bfr(a);
}

// ---------------------------------------------------------------------------
// Fused weight prep: 3x wkT + 3x catT + 2x w1T, plus workspace zeroing tail
// (absorbs the old k_zero launch; zbuf spans sumA|outacc|ssq|cnt contiguously).
__global__ __launch_bounds__(256) void k_prep(
    const float* __restrict__ wk0, const float* __restrict__ wk1, const float* __restrict__ wk2,
    const float* __restrict__ w20, const float* __restrict__ ws0,
    const float* __restrict__ w21, const float* __restrict__ ws1,
    const float* __restrict__ w22, const float* __restrict__ ws2,
    const float* __restrict__ w1_1, const float* __restrict__ w1_2,
    short* __restrict__ wkT0, short* __restrict__ wkT1, short* __restrict__ wkT2,
    short* __restrict__ cat0, short* __restrict__ cat1, short* __restrict__ cat2,
    short* __restrict__ w1T1, short* __restrict__ w1T2,
    float* __restrict__ zbuf)
{
    const int i = blockIdx.x * 256 + threadIdx.x;
    if (i < 3*61440) {
        const int l = i / 61440, r = i % 61440;
        const int n = r / 960, k = r % 960;
        const float* wk = (l == 0) ? wk0 : (l == 1) ? wk1 : wk2;
        short* dst = (l == 0) ? wkT0 : (l == 1) ? wkT1 : wkT2;
        dst[r] = bfr(wk[k*64 + n]);
    } else {
        int j = i - 3*61440;
        if (j < 16384) {
            const int n = j / 128, k = j % 128;
            cat0[j] = bfr(k < 64 ? w20[k*128 + n] : ws0[(k-64)*128 + n]);
        } else if (j < 16384 + 24576) {
            j -= 16384;
            const int n = j / 192, k = j % 192;
            cat1[j] = bfr(k < 64 ? w21[k*128 + n] : ws1[(k-64)*128 + n]);
        } else if (j < 16384 + 49152) {
            j -= 16384 + 24576;
            const int n = j / 192, k = j % 192;
            cat2[j] = bfr(k < 64 ? w22[k*128 + n] : ws2[(k-64)*128 + n]);
        } else if (j < 16384 + 49152 + 8192) {
            j -= 16384 + 49152;
            const int n = j / 128, k = j % 128;
            w1T1[j] = bfr(w1_1[k*64 + n]);
        } else if (j < 16384 + 49152 + 16384) {
            j -= 16384 + 49152 + 8192;
            const int n = j / 128, k = j % 128;
            w1T2[j] = bfr(w1_2[k*64 + n]);
        } else {
            const int z = j - (16384 + 49152 + 16384);
            if (z < ZERON) zbuf[z] = 0.f;
        }
    }
}

// ---------------------------------------------------------------------------
// Compaction with wave-aggregated atomics (round-10 verified).
__global__ __launch_bounds__(256) void k_compact(
    const int* __restrict__ m, int* __restrict__ compact, int* __restrict__ cnt,
    int* __restrict__ idx)
{
    const int p = blockIdx.x * 256 + threadIdx.x;
    const int b = p >> 11, n = p & (N-1);
    const int lane = threadIdx.x & 63;
    const bool unm = (m[p] == 0);
    const unsigned long long mask = __ballot(unm);
    int base = 0;
    if (lane == 0) base = atomicAdd(&cnt[b], __popcll(mask));
    base = __shfl(base, 0, 64);
    if (unm) {
        const int pos = base + __popcll(mask & ((1ull << lane) - 1ull));
        compact[b*N + pos] = n;
    } else {
        #pragma unroll
        for (int k = 0; k < KNBR; k++) idx[(size_t)p*KNBR + k] = k;
    }
}

// ---------------------------------------------------------------------------
// PointNet + FUSED layer-0 unary (x1 = lrelu(feat@W1)), bf16 x1 out.
__global__ __launch_bounds__(256) void k_pointnet(
    const float* __restrict__ x, const int* __restrict__ m,
    const float* __restrict__ w1, const float* __restrict__ b1,
    const float* __restrict__ w2, const float* __restrict__ b2,
    const float* __restrict__ wu,
    float* __restrict__ feat, float4* __restrict__ coords4,
    unsigned short* __restrict__ x1out)
{
    __shared__ float s_x[32][3];
    __shared__ __align__(16) float s_hT[64*40];
    __shared__ __align__(16) float s_fT[64*40];
    const int tid = threadIdx.x;
    const int pbase = blockIdx.x * 32;
    if (tid < 32) {
        const int p = pbase + tid;
        const float x0 = x[p*3+0], x1v = x[p*3+1], x2v = x[p*3+2];
        s_x[tid][0] = x0; s_x[tid][1] = x1v; s_x[tid][2] = x2v;
        const bool mm = (m[p] != 0);
        const float cx = mm ? 1e6f : x0, cy = mm ? 1e6f : x1v, cz = mm ? 1e6f : x2v;
        coords4[p] = make_float4(cx, cy, cz, cx*cx + cy*cy + cz*cz);
    }
    __syncthreads();
    const int w = tid >> 6, c = tid & 63;
    const int pb = w * 8;
    {
        const float w10 = w1[c], w11 = w1[64+c], w12 = w1[128+c], bb = b1[c];
        #pragma unroll
        for (int pl = 0; pl < 8; pl++) {
            float s = bb;
            s = fmaf(s_x[pb+pl][0], w10, s);
            s = fmaf(s_x[pb+pl][1], w11, s);
            s = fmaf(s_x[pb+pl][2], w12, s);
            s_hT[c*40 + pb + pl] = fmaxf(s, 0.f);
        }
    }
    {
        float acc[8];
        const float bb = b2[c];
        #pragma unroll
        for (int pl = 0; pl < 8; pl++) acc[pl] = bb;
        for (int j = 0; j < 64; j++) {
            const float wv = w2[j*64 + c];
            const float4 h0 = *(const float4*)&s_hT[j*40 + pb];
            const float4 h1 = *(const float4*)&s_hT[j*40 + pb + 4];
            acc[0] = fmaf(h0.x, wv, acc[0]); acc[1] = fmaf(h0.y, wv, acc[1]);
            acc[2] = fmaf(h0.z, wv, acc[2]); acc[3] = fmaf(h0.w, wv, acc[3]);
            acc[4] = fmaf(h1.x, wv, acc[4]); acc[5] = fmaf(h1.y, wv, acc[5]);
            acc[6] = fmaf(h1.z, wv, acc[6]); acc[7] = fmaf(h1.w, wv, acc[7]);
        }
        #pragma unroll
        for (int pl = 0; pl < 8; pl++) {
            const float fv = fmaxf(acc[pl], 0.f);
            feat[(size_t)(pbase + pb + pl)*64 + c] = fv;
            s_fT[c*40 + pb + pl] = fv;
        }
    }
    __syncthreads();
    // stage 3: x1 = lrelu(feat @ wu), bf16 out
    {
        float acc[8] = {0.f,0.f,0.f,0.f,0.f,0.f,0.f,0.f};
        for (int j = 0; j < 64; j++) {
            const float wv = wu[j*64 + c];
            const float4 f0 = *(const float4*)&s_fT[j*40 + pb];
            const float4 f1 = *(const float4*)&s_fT[j*40 + pb + 4];
            acc[0] = fmaf(f0.x, wv, acc[0]); acc[1] = fmaf(f0.y, wv, acc[1]);
            acc[2] = fmaf(f0.z, wv, acc[2]); acc[3] = fmaf(f0.w, wv, acc[3]);
            acc[4] = fmaf(f1.x, wv, acc[4]); acc[5] = fmaf(f1.y, wv, acc[5]);
            acc[6] = fmaf(f1.z, wv, acc[6]); acc[7] = fmaf(f1.w, wv, acc[7]);
        }
        #pragma unroll
        for (int pl = 0; pl < 8; pl++)
            x1out[(size_t)(pbase + pb + pl)*64 + c] = (unsigned short)bfr(lrelu(acc[pl]));
    }
}

// ---------------------------------------------------------------------------
// KNN — 512 threads (8 queries/block); round-5 measured: dropped below the
// 49.6 µs top-5 cutoff (was 68.6 µs at 256 threads).
__global__ __launch_bounds__(512, 8) void k_knn(
    const float4* __restrict__ c4, const int* __restrict__ compact,
    const int* __restrict__ cnt, int* __restrict__ idx)
{
    const int b = blockIdx.x >> 8;
    const int slot0 = (blockIdx.x & 255) * 8;
    const int cn = cnt[b];
    if (slot0 >= cn) return;
    __shared__ float4 s_c[N];
    const int tid = threadIdx.x;
    const int w = tid >> 6, lane = tid & 63;
    for (int i = tid; i < N; i += 512) s_c[i] = c4[(size_t)b*N + i];
    __syncthreads();
    const int slot = slot0 + w;
    const bool active = slot < cn;
    const int n = active ? compact[b*N + slot] : 0;
    const float4 me = s_c[n];

    unsigned A[32];
    #pragma unroll
    for (int j = 0; j < 32; j++) {
        const float4 s = s_c[j*64 + lane];
        float d2 = me.w + s.w - 2.f*(me.x*s.x + me.y*s.y + me.z*s.z);
        d2 = fmaxf(d2, 0.f);
        A[j] = (__float_as_uint(d2) & 0xFFFFF800u) | (unsigned)(j*64 + lane);
    }
    #pragma unroll
    for (int k = 2; k <= 32; k <<= 1) {
        #pragma unroll
        for (int j = k >> 1; j > 0; j >>= 1) {
            #pragma unroll
            for (int i = 0; i < 32; i++) {
                const int l = i ^ j;
                if (l > i) {
                    const unsigned lo = umin_(A[i], A[l]);
                    const unsigned hi = umax_(A[i], A[l]);
                    const bool up = ((i & k) == 0);
                    A[i] = up ? lo : hi;
                    A[l] = up ? hi : lo;
                }
            }
        }
    }
    #pragma unroll
    for (int r = 0; r < 6; r++) {
        const int mask = 1 << r;
        #pragma unroll
        for (int i = 0; i < 16; i++) {
            const unsigned t1 = (unsigned)__shfl_xor((int)A[31-i], mask, 64);
            const unsigned t2 = (unsigned)__shfl_xor((int)A[i],    mask, 64);
            A[i]    = umin_(A[i],    t1);
            A[31-i] = umin_(A[31-i], t2);
        }
        if (r < 5) {
            #pragma unroll
            for (int j = 16; j > 0; j >>= 1) {
                #pragma unroll
                for (int i = 0; i < 32; i++) {
                    const int l = i ^ j;
                    if (l > i) {
                        const unsigned lo = umin_(A[i], A[l]);
                        A[l] = umax_(A[i], A[l]);
                        A[i] = lo;
                    }
                }
            }
        }
    }
    #pragma unroll
    for (int s = 16; s >= 1; s >>= 1) {
        #pragma unroll
        for (int i = 0; i < s; i++)
            A[i] = (lane & s) ? A[i+s] : A[i];
    }
    if (active && lane < 32)
        idx[(size_t)(b*N + n)*KNBR + lane] = (int)(A[0] & 0x7FFu);
}

// ---------------------------------------------------------------------------
// KPConv, 16 pts/block, 512 threads, all-MFMA, bf16 x1 gather, fused phase 4.
// Round-5 LDS-conflict fixes (counter: SQ_LDS_BANK_CONFLICT = 4.06M/dispatch):
//  - AS 976 -> 984: phase-2 aggT row stride 492 dwords == 12 (mod 32) -> lanes
//    0..7 tile all 32 banks exactly; lanes 8..15 repeat -> free 2-way
//    (was == 8 mod 32 -> 4-way conflict on every ds_read_b128).
//  - Phase-1 aggT store had n*32 == 0 (mod 32): 15 lanes/q-group hit ONE
//    bank-pair (~15-way). Fix: XOR-swizzle ch-block bits by (kp&3) on both
//    the store and the phase-2 read -> 16 bank-pairs/store (~4-way, which is
//    the 120-dword/32-bank floor). Pure LDS layout change; MFMA data unchanged.
template<int CIN, bool FUSE>
__global__ __launch_bounds__(512) void k_kpconv(
    const unsigned short* __restrict__ x1, const float4* __restrict__ c4,
    const float* __restrict__ kp,
    const int* __restrict__ idx, const float* __restrict__ feat_in,
    const short* __restrict__ WkT, const short* __restrict__ WcatT,
    const short* __restrict__ W1T, unsigned short* __restrict__ x1out,
    float* __restrict__ out)
{
    constexpr int KC = 64 + CIN;   // phase-3 K extent
    constexpr int AS = 984;        // aggT row stride (shorts); 492 dw == 12 mod 32
    constexpr int XS = 72;         // x2 row stride (shorts)
    constexpr int FS = CIN + 8;    // feat row stride (shorts)
    constexpr int PS = 65;         // partial row stride (floats)
    constexpr int FOS = 136;       // fused fout row stride (shorts)
    __shared__ __align__(16) short s_aggT[16*AS];      // 31488 B
    __shared__ __align__(16) unsigned s_un[11264];     // 45056 B union region
    __shared__ int   s_idx[512];
    __shared__ float skp[48];

    const int tid   = threadIdx.x;
    const int pbase = blockIdx.x * 16;
    const int brow  = pbase & ~(N-1);
    const int w = tid >> 6, lane = tid & 63;

    if (tid < NKP*3) skp[tid] = kp[tid];
    s_idx[tid] = idx[(size_t)pbase*KNBR + tid];
    __syncthreads();

    // ---- phase 1: wave w -> points 2w, 2w+1 (per-wave, no barriers) ----
    unsigned* xg  = s_un + w*1408;                    // [64 ch][18 dwords]
    short*    wbf = (short*)(s_un + w*1408 + 1152);   // [16 kp][32 nbr]

    for (int sub = 0; sub < 2; sub++) {
        const int pl = w*2 + sub;
        {
            const int k = lane & 31, h = lane >> 5;
            const float4 cp = c4[pbase + pl];
            const float4 cn = c4[brow + s_idx[pl*KNBR + k]];
            const float dx = cn.x - cp.x, dy = cn.y - cp.y, dz = cn.z - cp.z;
            #pragma unroll
            for (int j = 0; j < 8; j++) {
                const int kpi = h*8 + j;
                if (kpi < NKP) {
                    const float ex = dx - skp[kpi*3], ey = dy - skp[kpi*3+1], ez = dz - skp[kpi*3+2];
                    const float dist = sqrtf(ex*ex + ey*ey + ez*ez);
                    wbf[kpi*32 + k] = bfr(fmaxf(0.f, 1.f - dist*2.f));
                }
            }
        }
        {
            unsigned short g[KNBR];
            #pragma unroll
            for (int k = 0; k < KNBR; k++)
                g[k] = x1[(size_t)(brow + s_idx[pl*KNBR + k])*64 + lane];
            #pragma unroll
            for (int i = 0; i < 16; i++)
                xg[lane*18 + i] = (unsigned)g[2*i] | ((unsigned)g[2*i+1] << 16);
        }
        {
            const int n = lane & 15, q = lane >> 4;
            const bf16x8 bw = *(const bf16x8*)&wbf[n*32 + q*8];
            #pragma unroll
            for (int t = 0; t < 4; t++) {
                union { unsigned u[4]; bf16x8 v; } af;
                const unsigned* src = &xg[(t*16 + n)*18 + q*4];
                af.u[0] = src[0]; af.u[1] = src[1]; af.u[2] = src[2]; af.u[3] = src[3];
                fx4 d = {0.f,0.f,0.f,0.f};
                d = __builtin_amdgcn_mfma_f32_16x16x32_bf16(af.v, bw, d, 0, 0, 0);
                if (n < NKP) {
                    const uint2 o = make_uint2(pk2(d[0], d[1]), pk2(d[2], d[3]));
                    // ch-block XOR swizzle by (kp&3): spreads the 15-way
                    // same-bank store across 16 bank-pairs.
                    *(uint2*)&s_aggT[pl*AS + n*64 + ((t ^ (n & 3))<<4) + q*4] = o;
                }
            }
        }
    }
    __syncthreads();   // phase-1 region dead; union re-partitioned:

    short* s_x2bf   = (short*)s_un;                        // [16][XS]
    short* s_featbf = (short*)s_un + 16*XS;                // [16][FS]
    float* s_part   = (float*)((char*)s_un + 6656);        // [2][16][PS]

    for (int i = tid; i < 16*CIN; i += 512) {
        const int p = i / CIN, j = i % CIN;
        s_featbf[p*FS + j] = bfr(feat_in[(size_t)pbase*CIN + i]);
    }

    const int nlane = lane & 15, q = lane >> 4;
    // phase 2: x2 = lrelu(agg @ Wk). wave w -> col-tile (w&3), K-half (w>>2).
    {
        const int ct = w & 3, kh = w >> 2;
        fx4 acc = {0.f,0.f,0.f,0.f};
        const short* abase = &s_aggT[nlane*AS];
        const short* brw  = &WkT[(size_t)(ct*16 + nlane)*960 + kh*480];
        const int obase = kh*480 + q*8;
        for (int t = 0; t < 15; t++) {
            const int O  = obase + t*32;                  // logical K offset
            const int Os = O ^ (((O >> 6) & 3) << 4);     // match store swizzle
            const bf16x8 af = *(const bf16x8*)&abase[Os];
            const bf16x8 bf = *(const bf16x8*)&brw[t*32 + q*8];
            acc = __builtin_amdgcn_mfma_f32_16x16x32_bf16(af, bf, acc, 0, 0, 0);
        }
        float* pp = s_part + kh*(16*PS);
        #pragma unroll
        for (int r = 0; r < 4; r++)
            pp[(q*4+r)*PS + ct*16 + nlane] = acc[r];
    }
    __syncthreads();
    for (int i = tid; i < 1024; i += 512) {
        const int pt = i >> 6, c = i & 63;
        const float v = s_part[pt*PS + c] + s_part[16*PS + pt*PS + c];
        s_x2bf[pt*XS + c] = bfr(lrelu(v));
    }
    __syncthreads();

    // phase 3: out = lrelu([x2|feat] @ [W2;Ws]). wave w -> cols [16w,16w+16).
    fx4 acc0 = {0.f,0.f,0.f,0.f};
    {
        const short* b0r = &WcatT[(size_t)(w*16 + nlane)*KC];
        const short* xrow = &s_x2bf[nlane*XS];
        const short* frow = &s_featbf[nlane*FS];
        #pragma unroll
        for (int t = 0; t < KC/32; t++) {
            const int k0 = t*32 + q*8;
            const short* src = (t < 2) ? &xrow[k0] : &frow[k0 - 64];
            const bf16x8 af = *(const bf16x8*)src;
            const bf16x8 b0 = *(const bf16x8*)&b0r[k0];
            acc0 = __builtin_amdgcn_mfma_f32_16x16x32_bf16(af, b0, acc0, 0, 0, 0);
        }
        #pragma unroll
        for (int r = 0; r < 4; r++)
            out[(size_t)(pbase + q*4 + r)*128 + w*16 + nlane] = lrelu(acc0[r]);
    }

    if (FUSE) {
        // phase 4: x1out = lrelu(out @ W1) for the NEXT layer, in-block.
        __syncthreads();   // all phase-3 LDS reads done; re-alias s_un
        short* s_fout = (short*)s_un;   // [16][FOS]
        #pragma unroll
        for (int r = 0; r < 4; r++)
            s_fout[(q*4 + r)*FOS + w*16 + nlane] = bfr(lrelu(acc0[r]));
        __syncthreads();
        if (w < 4) {
            fx4 acc = {0.f,0.f,0.f,0.f};
            const short* arow = &s_fout[nlane*FOS];
            const short* brw  = &W1T[(size_t)(w*16 + nlane)*128];
            #pragma unroll
            for (int t = 0; t < 4; t++) {
                const int k0 = t*32 + q*8;
                const bf16x8 af = *(const bf16x8*)&arow[k0];
                const bf16x8 bf = *(const bf16x8*)&brw[k0];
                acc = __builtin_amdgcn_mfma_f32_16x16x32_bf16(af, bf, acc, 0, 0, 0);
            }
            #pragma unroll
            for (int r = 0; r < 4; r++)
                x1out[(size_t)(pbase + q*4 + r)*64 + w*16 + nlane] =
                    (unsigned short)bfr(lrelu(acc[r]));
        }
    }
}

// ---------------------------------------------------------------------------
__global__ __launch_bounds__(256) void k_vlad_a(
    const float* __restrict__ f, const float* __restrict__ wa,
    const int* __restrict__ m, float* __restrict__ a, float* __restrict__ sumA)
{
    __shared__ __align__(16) float s_fT[128*36 + 8];
    __shared__ float s_m[32];
    const int tid = threadIdx.x;
    const int pbase = blockIdx.x * 32;
    const int b = pbase >> 11;
    for (int i = tid; i < 32*128; i += 256) {
        const int p = i >> 7, j = i & 127;
        s_fT[j*36 + p] = f[(size_t)pbase*128 + i];
    }
    if (tid < 32) s_m[tid] = (m[pbase + tid] != 0) ? 0.f : 1.f;
    __syncthreads();
    const int w = tid >> 6, kc = tid & 63;
    const int pb = w * 8;
    float acc[8] = {0.f,0.f,0.f,0.f,0.f,0.f,0.f,0.f};
    for (int j = 0; j < 128; j++) {
        const float wv = wa[j*64 + kc];
        const float4 f0 = *(const float4*)&s_fT[j*36 + pb];
        const float4 f1 = *(const float4*)&s_fT[j*36 + pb + 4];
        acc[0] = fmaf(f0.x, wv, acc[0]); acc[1] = fmaf(f0.y, wv, acc[1]);
        acc[2] = fmaf(f0.z, wv, acc[2]); acc[3] = fmaf(f0.w, wv, acc[3]);
        acc[4] = fmaf(f1.x, wv, acc[4]); acc[5] = fmaf(f1.y, wv, acc[5]);
        acc[6] = fmaf(f1.z, wv, acc[6]); acc[7] = fmaf(f1.w, wv, acc[7]);
    }
    float part = 0.f;
    #pragma unroll
    for (int pl = 0; pl < 8; pl++) {
        float mx = acc[pl];
        #pragma unroll
        for (int off = 32; off > 0; off >>= 1) mx = fmaxf(mx, __shfl_xor(mx, off, 64));
        const float e = expf(acc[pl] - mx);
        float se = e;
        #pragma unroll
        for (int off = 32; off > 0; off >>= 1) se += __shfl_xor(se, off, 64);
        const float av = (e / se) * s_m[pb + pl];
        a[(size_t)(pbase + pb + pl)*64 + kc] = av;
        part += av;
    }
    atomicAdd(&sumA[b*64 + kc], part);
}

// ---------------------------------------------------------------------------
__global__ __launch_bounds__(256) void k_vlad_acc(
    const float* __restrict__ a, const float* __restrict__ f,
    float* __restrict__ vpart)
{
    __shared__ __align__(16) float s_a[32*64];
    __shared__ __align__(16) float s_f[32*128];
    const int b  = blockIdx.x >> 5;          // VCH=32
    const int ch = blockIdx.x & 31;
    const int n0 = ch * (N / VCH);
    const int tid = threadIdx.x;
    const int kc0 = (tid >> 5) * 8;
    const int d0  = (tid & 31) * 4;
    float acc[8][4];
    #pragma unroll
    for (int i = 0; i < 8; i++)
        #pragma unroll
        for (int j = 0; j < 4; j++) acc[i][j] = 0.f;
    for (int t = 0; t < N/VCH; t += 32) {
        __syncthreads();
        const size_t base = (size_t)(b*N + n0 + t);
        for (int i = tid; i < 32*64; i += 256)  s_a[i] = a[(base << 6) + i];
        for (int i = tid; i < 32*128; i += 256) s_f[i] = f[(base << 7) + i];
        __syncthreads();
        for (int n = 0; n < 32; n++) {
            const float4 a0 = *(const float4*)&s_a[n*64 + kc0];
            const float4 a1 = *(const float4*)&s_a[n*64 + kc0 + 4];
            const float4 fv = *(const float4*)&s_f[n*128 + d0];
            const float av[8] = {a0.x,a0.y,a0.z,a0.w,a1.x,a1.y,a1.z,a1.w};
            const float fw[4] = {fv.x,fv.y,fv.z,fv.w};
            #pragma unroll
            for (int i = 0; i < 8; i++)
                #pragma unroll
                for (int j = 0; j < 4; j++) acc[i][j] = fmaf(av[i], fw[j], acc[i][j]);
        }
    }
    float* vp = vpart + ((size_t)ch*B + b)*8192;
    #pragma unroll
    for (int i = 0; i < 8; i++)
        #pragma unroll
        for (int j = 0; j < 4; j++) vp[(kc0+i)*128 + d0 + j] = acc[i][j];
}

// ---------------------------------------------------------------------------
// Intra-normalize; also accumulates the per-batch global sum-of-squares.
__global__ __launch_bounds__(128) void k_vlad_norm(
    const float* __restrict__ vpart, const float* __restrict__ sumA,
    const float* __restrict__ centers, float* __restrict__ v,
    float* __restrict__ ssq)
{
    const int b = blockIdx.x >> 6, kc = blockIdx.x & 63, d = threadIdx.x;
    float acc = 0.f;
    #pragma unroll
    for (int c = 0; c < VCH; c++)
        acc += vpart[((size_t)c*B + b)*8192 + kc*128 + d];
    const float vv = acc - sumA[b*64 + kc] * centers[kc*128 + d];
    float s2 = vv*vv;
    #pragma unroll
    for (int off = 32; off > 0; off >>= 1) s2 += __shfl_xor(s2, off, 64);
    __shared__ float red[2];
    if ((d & 63) == 0) red[d >> 6] = s2;
    __syncthreads();
    const float tot = red[0] + red[1];
    const float s = sqrtf(tot) + 1e-8f;
    v[((size_t)b*64 + kc)*128 + d] = vv / s;
    if (d == 0) atomicAdd(&ssq[b], tot / (s*s));
}

// ---------------------------------------------------------------------------
// Round-5: grid 32 -> 128 (j-chunks of 64). Was using 32/256 CUs to stream
// the 8 MB proj matrix; more blocks = more parallel HBM streams.
__global__ __launch_bounds__(256) void k_proj(
    const float* __restrict__ v, const float* __restrict__ ssq,
    const float* __restrict__ proj, float* __restrict__ outacc)
{
    __shared__ __align__(16) float s_v[8*64];
    __shared__ float s_sc[8];
    const int jc = blockIdx.x, o = threadIdx.x;
    const int j0 = jc * 64;
    for (int i = o; i < 8*64; i += 256) {
        const int bb = i >> 6, jj = i & 63;
        s_v[i] = v[(size_t)bb*8192 + j0 + jj];
    }
    if (o < 8) s_sc[o] = 1.f / (sqrtf(ssq[o]) + 1e-8f);
    __syncthreads();
    float acc[8] = {0.f,0.f,0.f,0.f,0.f,0.f,0.f,0.f};
    for (int jj = 0; jj < 64; jj += 4) {
        float pv[4];
        #pragma unroll
        for (int q = 0; q < 4; q++) pv[q] = proj[(size_t)(j0+jj+q)*256 + o];
        #pragma unroll
        for (int bb = 0; bb < 8; bb++) {
            const float4 vv = *(const float4*)&s_v[bb*64 + jj];
            acc[bb] = fmaf(vv.x, pv[0], acc[bb]);
            acc[bb] = fmaf(vv.y, pv[1], acc[bb]);
            acc[bb] = fmaf(vv.z, pv[2], acc[bb]);
            acc[bb] = fmaf(vv.w, pv[3], acc[bb]);
        }
    }
    #pragma unroll
    for (int bb = 0; bb < 8; bb++) atomicAdd(&outacc[bb*256 + o], acc[bb] * s_sc[bb]);
}

__global__ __launch_bounds__(256) void k_outnorm(
    const float* __restrict__ outacc, float* __restrict__ out)
{
    const int b = blockIdx.x, o = threadIdx.x;
    const float val = outacc[b*256 + o];
    float s = val*val;
    #pragma unroll
    for (int off = 32; off > 0; off >>= 1) s += __shfl_xor(s, off, 64);
    __shared__ float red[4];
    if ((o & 63) == 0) red[o >> 6] = s;
    __syncthreads();
    const float tot = red[0] + red[1] + red[2] + red[3];
    out[b*256 + o] = val / (sqrtf(tot) + 1e-12f);
}

// ---------------------------------------------------------------------------
extern "C" void kernel_launch(void* const* d_in, const int* in_sizes, int n_in,
                              void* d_out, int out_size, void* d_ws, size_t ws_size,
                              hipStream_t stream)
{
    (void)in_sizes; (void)n_in; (void)out_size; (void)ws_size;
    const float* x     = (const float*)d_in[0];
    const int*   m     = (const int*)  d_in[1];
    const float* pn_w1 = (const float*)d_in[2];
    const float* pn_b1 = (const float*)d_in[3];
    const float* pn_w2 = (const float*)d_in[4];
    const float* pn_b2 = (const float*)d_in[5];
    const float* kp    = (const float*)d_in[6];
    const float* bw1[3] = {(const float*)d_in[7],  (const float*)d_in[11], (const float*)d_in[15]};
    const float* bwk[3] = {(const float*)d_in[8],  (const float*)d_in[12], (const float*)d_in[16]};
    const float* bw2[3] = {(const float*)d_in[9],  (const float*)d_in[13], (const float*)d_in[17]};
    const float* bws[3] = {(const float*)d_in[10], (const float*)d_in[14], (const float*)d_in[18]};
    const float* vlad_wa      = (const float*)d_in[19];
    const float* vlad_centers = (const float*)d_in[20];
    const float* vlad_proj    = (const float*)d_in[21];
    float* out = (float*)d_out;

    char* ws = (char*)d_ws;
    size_t off = 0;
    auto alloc = [&](size_t bytes) -> void* {
        void* p = ws + off;
        off = (off + bytes + 255) & ~(size_t)255;
        return p;
    };
    float4* coords4 = (float4*)alloc((size_t)BN*16);
    float*  feat0   = (float*)alloc((size_t)BN*64*4);
    int*    idxb    = (int*)  alloc((size_t)BN*KNBR*4);
    unsigned short* x1A = (unsigned short*)alloc((size_t)BN*64*2);  // bf16 ping
    unsigned short* x1B = (unsigned short*)alloc((size_t)BN*64*2);  // bf16 pong
    float*  fA      = (float*)alloc((size_t)BN*128*4);
    float*  fB      = (float*)alloc((size_t)BN*128*4);
    float*  abuf    = (float*)alloc((size_t)BN*64*4);
    float*  vbuf    = (float*)alloc((size_t)B*8192*4);
    // contiguous zero region (k_prep tail): sumA | outacc | ssqb | cntb
    float*  sumA    = (float*)alloc((size_t)B*64*4);    // 2048 B (256-aligned)
    float*  outacc  = (float*)alloc((size_t)B*256*4);   // 8192 B
    float*  ssqb    = (float*)alloc((size_t)B*4);       // padded to 256 B
    int*    cntb    = (int*)  alloc((size_t)B*4);
    int*    compact = (int*)alloc((size_t)BN*4);
    short*  wkT[3]  = {(short*)alloc(64*960*2), (short*)alloc(64*960*2), (short*)alloc(64*960*2)};
    short*  catT[3] = {(short*)alloc(128*192*2), (short*)alloc(128*192*2), (short*)alloc(128*192*2)};
    short*  w1T1    = (short*)alloc(64*128*2);
    short*  w1T2    = (short*)alloc(64*128*2);
    float*  vpart   = fB;   // fB dead after layer-2 reads it; 8 MB fits VCH=32 exactly

    k_prep<<<(3*61440 + 81920 + ZERON + 255)/256, 256, 0, stream>>>(
        bwk[0], bwk[1], bwk[2], bw2[0], bws[0], bw2[1], bws[1], bw2[2], bws[2],
        bw1[1], bw1[2],
        wkT[0], wkT[1], wkT[2], catT[0], catT[1], catT[2], w1T1, w1T2, sumA);

    k_compact<<<BN/256, 256, 0, stream>>>(m, compact, cntb, idxb);
    k_pointnet<<<BN/32, 256, 0, stream>>>(x, m, pn_w1, pn_b1, pn_w2, pn_b2, bw1[0],
                                          feat0, coords4, x1A);
    k_knn<<<B*256, 512, 0, stream>>>(coords4, compact, cntb, idxb);

    k_kpconv<64,true>  <<<BN/16, 512, 0, stream>>>(x1A, coords4, kp, idxb, feat0, wkT[0], catT[0], w1T1, x1B, fA);
    k_kpconv<128,true> <<<BN/16, 512, 0, stream>>>(x1B, coords4, kp, idxb, fA,    wkT[1], catT[1], w1T2, x1A, fB);
    k_kpconv<128,false><<<BN/16, 512, 0, stream>>>(x1A, coords4, kp, idxb, fB,    wkT[2], catT[2], nullptr, nullptr, fA);

    k_vlad_a<<<BN/32, 256, 0, stream>>>(fA, vlad_wa, m, abuf, sumA);
    k_vlad_acc<<<B*VCH, 256, 0, stream>>>(abuf, fA, vpart);
    k_vlad_norm<<<B*64, 128, 0, stream>>>(vpart, sumA, vlad_centers, vbuf, ssqb);
    k_proj<<<128, 256, 0, stream>>>(vbuf, ssqb, vlad_proj, outacc);
    k_outnorm<<<B, 256, 0, stream>>>(outacc, out);
}

// Round 10
// 305.844 us; speedup vs baseline: 1.1894x; 1.0325x over previous
//
#include <hip/hip_runtime.h>
#include <hip/hip_bf16.h>

#define B 8
#define N 2048
#define BN (B*N)
#define KNBR 32
#define NKP 15
#define VCH 32   // n-chunks per batch in VLAD accumulation (32 -> 256 blocks)

#define ZERON 2632   // floats zeroed by k_prep tail: sumA(512)+outacc(2048)+ssq(64 pad)+cnt(8)

__device__ __forceinline__ float lrelu(float x){ return x > 0.f ? x : 0.1f*x; }
__device__ __forceinline__ unsigned umin_(unsigned a, unsigned b){ return __builtin_elementwise_min(a, b); }
__device__ __forceinline__ unsigned umax_(unsigned a, unsigned b){ return __builtin_elementwise_max(a, b); }

// MFMA fragment types (per guide: short8 = 8 bf16 = 4 VGPRs)
typedef __attribute__((ext_vector_type(8))) short bf16x8;
typedef __attribute__((ext_vector_type(4))) float fx4;

__device__ __forceinline__ short bfr(float f){
    union { __hip_bfloat16 h; short s; } u;
    u.h = __float2bfloat16(f);
    return u.s;
}
__device__ __forceinline__ unsigned pk2(float a, float b){
    return ((unsigned)(unsigned short)bfr(b) << 16) | (unsigned)(unsigned short)bfr(a);
}

// ---------------------------------------------------------------------------
// Fused weight prep: 3x wkT + 3x catT + 2x w1T, plus workspace zeroing tail
// (absorbs the old k_zero launch; zbuf spans sumA|outacc|ssq|cnt contiguously).
__global__ __launch_bounds__(256) void k_prep(
    const float* __restrict__ wk0, const float* __restrict__ wk1, const float* __restrict__ wk2,
    const float* __restrict__ w20, const float* __restrict__ ws0,
    const float* __restrict__ w21, const float* __restrict__ ws1,
    const float* __restrict__ w22, const float* __restrict__ ws2,
    const float* __restrict__ w1_1, const float* __restrict__ w1_2,
    short* __restrict__ wkT0, short* __restrict__ wkT1, short* __restrict__ wkT2,
    short* __restrict__ cat0, short* __restrict__ cat1, short* __restrict__ cat2,
    short* __restrict__ w1T1, short* __restrict__ w1T2,
    float* __restrict__ zbuf)
{
    const int i = blockIdx.x * 256 + threadIdx.x;
    if (i < 3*61440) {
        const int l = i / 61440, r = i % 61440;
        const int n = r / 960, k = r % 960;
        const float* wk = (l == 0) ? wk0 : (l == 1) ? wk1 : wk2;
        short* dst = (l == 0) ? wkT0 : (l == 1) ? wkT1 : wkT2;
        dst[r] = bfr(wk[k*64 + n]);
    } else {
        int j = i - 3*61440;
        if (j < 16384) {
            const int n = j / 128, k = j % 128;
            cat0[j] = bfr(k < 64 ? w20[k*128 + n] : ws0[(k-64)*128 + n]);
        } else if (j < 16384 + 24576) {
            j -= 16384;
            const int n = j / 192, k = j % 192;
            cat1[j] = bfr(k < 64 ? w21[k*128 + n] : ws1[(k-64)*128 + n]);
        } else if (j < 16384 + 49152) {
            j -= 16384 + 24576;
            const int n = j / 192, k = j % 192;
            cat2[j] = bfr(k < 64 ? w22[k*128 + n] : ws2[(k-64)*128 + n]);
        } else if (j < 16384 + 49152 + 8192) {
            j -= 16384 + 49152;
            const int n = j / 128, k = j % 128;
            w1T1[j] = bfr(w1_1[k*64 + n]);
        } else if (j < 16384 + 49152 + 16384) {
            j -= 16384 + 49152 + 8192;
            const int n = j / 128, k = j % 128;
            w1T2[j] = bfr(w1_2[k*64 + n]);
        } else {
            const int z = j - (16384 + 49152 + 16384);
            if (z < ZERON) zbuf[z] = 0.f;
        }
    }
}

// ---------------------------------------------------------------------------
// Compaction with wave-aggregated atomics (round-10 verified).
__global__ __launch_bounds__(256) void k_compact(
    const int* __restrict__ m, int* __restrict__ compact, int* __restrict__ cnt,
    int* __restrict__ idx)
{
    const int p = blockIdx.x * 256 + threadIdx.x;
    const int b = p >> 11, n = p & (N-1);
    const int lane = threadIdx.x & 63;
    const bool unm = (m[p] == 0);
    const unsigned long long mask = __ballot(unm);
    int base = 0;
    if (lane == 0) base = atomicAdd(&cnt[b], __popcll(mask));
    base = __shfl(base, 0, 64);
    if (unm) {
        const int pos = base + __popcll(mask & ((1ull << lane) - 1ull));
        compact[b*N + pos] = n;
    } else {
        #pragma unroll
        for (int k = 0; k < KNBR; k++) idx[(size_t)p*KNBR + k] = k;
    }
}

// ---------------------------------------------------------------------------
// PointNet + FUSED layer-0 unary (x1 = lrelu(feat@W1)), bf16 x1 out.
__global__ __launch_bounds__(256) void k_pointnet(
    const float* __restrict__ x, const int* __restrict__ m,
    const float* __restrict__ w1, const float* __restrict__ b1,
    const float* __restrict__ w2, const float* __restrict__ b2,
    const float* __restrict__ wu,
    float* __restrict__ feat, float4* __restrict__ coords4,
    unsigned short* __restrict__ x1out)
{
    __shared__ float s_x[32][3];
    __shared__ __align__(16) float s_hT[64*40];
    __shared__ __align__(16) float s_fT[64*40];
    const int tid = threadIdx.x;
    const int pbase = blockIdx.x * 32;
    if (tid < 32) {
        const int p = pbase + tid;
        const float x0 = x[p*3+0], x1v = x[p*3+1], x2v = x[p*3+2];
        s_x[tid][0] = x0; s_x[tid][1] = x1v; s_x[tid][2] = x2v;
        const bool mm = (m[p] != 0);
        const float cx = mm ? 1e6f : x0, cy = mm ? 1e6f : x1v, cz = mm ? 1e6f : x2v;
        coords4[p] = make_float4(cx, cy, cz, cx*cx + cy*cy + cz*cz);
    }
    __syncthreads();
    const int w = tid >> 6, c = tid & 63;
    const int pb = w * 8;
    {
        const float w10 = w1[c], w11 = w1[64+c], w12 = w1[128+c], bb = b1[c];
        #pragma unroll
        for (int pl = 0; pl < 8; pl++) {
            float s = bb;
            s = fmaf(s_x[pb+pl][0], w10, s);
            s = fmaf(s_x[pb+pl][1], w11, s);
            s = fmaf(s_x[pb+pl][2], w12, s);
            s_hT[c*40 + pb + pl] = fmaxf(s, 0.f);
        }
    }
    {
        float acc[8];
        const float bb = b2[c];
        #pragma unroll
        for (int pl = 0; pl < 8; pl++) acc[pl] = bb;
        for (int j = 0; j < 64; j++) {
            const float wv = w2[j*64 + c];
            const float4 h0 = *(const float4*)&s_hT[j*40 + pb];
            const float4 h1 = *(const float4*)&s_hT[j*40 + pb + 4];
            acc[0] = fmaf(h0.x, wv, acc[0]); acc[1] = fmaf(h0.y, wv, acc[1]);
            acc[2] = fmaf(h0.z, wv, acc[2]); acc[3] = fmaf(h0.w, wv, acc[3]);
            acc[4] = fmaf(h1.x, wv, acc[4]); acc[5] = fmaf(h1.y, wv, acc[5]);
            acc[6] = fmaf(h1.z, wv, acc[6]); acc[7] = fmaf(h1.w, wv, acc[7]);
        }
        #pragma unroll
        for (int pl = 0; pl < 8; pl++) {
            const float fv = fmaxf(acc[pl], 0.f);
            feat[(size_t)(pbase + pb + pl)*64 + c] = fv;
            s_fT[c*40 + pb + pl] = fv;
        }
    }
    __syncthreads();
    // stage 3: x1 = lrelu(feat @ wu), bf16 out
    {
        float acc[8] = {0.f,0.f,0.f,0.f,0.f,0.f,0.f,0.f};
        for (int j = 0; j < 64; j++) {
            const float wv = wu[j*64 + c];
            const float4 f0 = *(const float4*)&s_fT[j*40 + pb];
            const float4 f1 = *(const float4*)&s_fT[j*40 + pb + 4];
            acc[0] = fmaf(f0.x, wv, acc[0]); acc[1] = fmaf(f0.y, wv, acc[1]);
            acc[2] = fmaf(f0.z, wv, acc[2]); acc[3] = fmaf(f0.w, wv, acc[3]);
            acc[4] = fmaf(f1.x, wv, acc[4]); acc[5] = fmaf(f1.y, wv, acc[5]);
            acc[6] = fmaf(f1.z, wv, acc[6]); acc[7] = fmaf(f1.w, wv, acc[7]);
        }
        #pragma unroll
        for (int pl = 0; pl < 8; pl++)
            x1out[(size_t)(pbase + pb + pl)*64 + c] = (unsigned short)bfr(lrelu(acc[pl]));
    }
}

// ---------------------------------------------------------------------------
// KNN — 512 threads (8 queries/block); round-7 measured 41.6 µs.
__global__ __launch_bounds__(512, 8) void k_knn(
    const float4* __restrict__ c4, const int* __restrict__ compact,
    const int* __restrict__ cnt, int* __restrict__ idx)
{
    const int b = blockIdx.x >> 8;
    const int slot0 = (blockIdx.x & 255) * 8;
    const int cn = cnt[b];
    if (slot0 >= cn) return;
    __shared__ float4 s_c[N];
    const int tid = threadIdx.x;
    const int w = tid >> 6, lane = tid & 63;
    for (int i = tid; i < N; i += 512) s_c[i] = c4[(size_t)b*N + i];
    __syncthreads();
    const int slot = slot0 + w;
    const bool active = slot < cn;
    const int n = active ? compact[b*N + slot] : 0;
    const float4 me = s_c[n];

    unsigned A[32];
    #pragma unroll
    for (int j = 0; j < 32; j++) {
        const float4 s = s_c[j*64 + lane];
        float d2 = me.w + s.w - 2.f*(me.x*s.x + me.y*s.y + me.z*s.z);
        d2 = fmaxf(d2, 0.f);
        A[j] = (__float_as_uint(d2) & 0xFFFFF800u) | (unsigned)(j*64 + lane);
    }
    #pragma unroll
    for (int k = 2; k <= 32; k <<= 1) {
        #pragma unroll
        for (int j = k >> 1; j > 0; j >>= 1) {
            #pragma unroll
            for (int i = 0; i < 32; i++) {
                const int l = i ^ j;
                if (l > i) {
                    const unsigned lo = umin_(A[i], A[l]);
                    const unsigned hi = umax_(A[i], A[l]);
                    const bool up = ((i & k) == 0);
                    A[i] = up ? lo : hi;
                    A[l] = up ? hi : lo;
                }
            }
        }
    }
    #pragma unroll
    for (int r = 0; r < 6; r++) {
        const int mask = 1 << r;
        #pragma unroll
        for (int i = 0; i < 16; i++) {
            const unsigned t1 = (unsigned)__shfl_xor((int)A[31-i], mask, 64);
            const unsigned t2 = (unsigned)__shfl_xor((int)A[i],    mask, 64);
            A[i]    = umin_(A[i],    t1);
            A[31-i] = umin_(A[31-i], t2);
        }
        if (r < 5) {
            #pragma unroll
            for (int j = 16; j > 0; j >>= 1) {
                #pragma unroll
                for (int i = 0; i < 32; i++) {
                    const int l = i ^ j;
                    if (l > i) {
                        const unsigned lo = umin_(A[i], A[l]);
                        A[l] = umax_(A[i], A[l]);
                        A[i] = lo;
                    }
                }
            }
        }
    }
    #pragma unroll
    for (int s = 16; s >= 1; s >>= 1) {
        #pragma unroll
        for (int i = 0; i < s; i++)
            A[i] = (lane & s) ? A[i+s] : A[i];
    }
    if (active && lane < 32)
        idx[(size_t)(b*N + n)*KNBR + lane] = (int)(A[0] & 0x7FFu);
}

// ---------------------------------------------------------------------------
// KPConv, 16 pts/block, 512 threads, all-MFMA, fused phase 4.
// Round-7 restructure: phase-1 A-fragments gathered DIRECTLY into registers.
// The old path was gather->VALU pack->LDS xg write->LDS b128 read->MFMA; but
// the lane(n,q) A-fragment mapping is bijective over the 32x64 tile, so each
// lane can load its own 32 ushorts (same total loads, bit-identical values)
// with zero packing and zero xg LDS. Frees 36 KB LDS: 78.8 -> ~48.7 KB
// -> 3 blocks/CU (was 2). Round-5 aggT swizzle retained.
template<int CIN, bool FUSE>
__global__ __launch_bounds__(512) void k_kpconv(
    const unsigned short* __restrict__ x1, const float4* __restrict__ c4,
    const float* __restrict__ kp,
    const int* __restrict__ idx, const float* __restrict__ feat_in,
    const short* __restrict__ WkT, const short* __restrict__ WcatT,
    const short* __restrict__ W1T, unsigned short* __restrict__ x1out,
    float* __restrict__ out)
{
    constexpr int KC = 64 + CIN;   // phase-3 K extent
    constexpr int AS = 984;        // aggT row stride (shorts); 492 dw == 12 mod 32
    constexpr int XS = 72;         // x2 row stride (shorts)
    constexpr int FS = CIN + 8;    // feat row stride (shorts)
    constexpr int PS = 65;         // partial row stride (floats)
    constexpr int FOS = 136;       // fused fout row stride (shorts)
    __shared__ __align__(16) short s_aggT[16*AS];      // 31488 B
    __shared__ __align__(16) unsigned s_un[3744];      // 14976 B union region
    __shared__ int   s_idx[512];
    __shared__ float skp[48];

    const int tid   = threadIdx.x;
    const int pbase = blockIdx.x * 16;
    const int brow  = pbase & ~(N-1);
    const int w = tid >> 6, lane = tid & 63;

    if (tid < NKP*3) skp[tid] = kp[tid];
    s_idx[tid] = idx[(size_t)pbase*KNBR + tid];
    __syncthreads();

    // ---- phase 1: wave w -> points 2w, 2w+1 (per-wave, no barriers) ----
    short* wbf = (short*)s_un + w*512;   // [16 kp][32 nbr] per wave (1 KB)

    for (int sub = 0; sub < 2; sub++) {
        const int pl = w*2 + sub;
        {
            const int k = lane & 31, h = lane >> 5;
            const float4 cp = c4[pbase + pl];
            const float4 cn = c4[brow + s_idx[pl*KNBR + k]];
            const float dx = cn.x - cp.x, dy = cn.y - cp.y, dz = cn.z - cp.z;
            #pragma unroll
            for (int j = 0; j < 8; j++) {
                const int kpi = h*8 + j;
                if (kpi < NKP) {
                    const float ex = dx - skp[kpi*3], ey = dy - skp[kpi*3+1], ez = dz - skp[kpi*3+2];
                    const float dist = sqrtf(ex*ex + ey*ey + ez*ez);
                    wbf[kpi*32 + k] = bfr(fmaxf(0.f, 1.f - dist*2.f));
                }
            }
        }
        {
            const int n = lane & 15, q = lane >> 4;
            // direct A-fragment gather: lane(n,q), t -> ch t*16+n, nbrs q*8+i.
            // Bit-identical to the old xg path: af[t].us[i] == old xg unpack.
            union { unsigned short us[8]; bf16x8 v; } af[4];
            #pragma unroll
            for (int i = 0; i < 8; i++) {
                const size_t row = (size_t)(brow + s_idx[pl*KNBR + q*8 + i])*64;
                #pragma unroll
                for (int t = 0; t < 4; t++)
                    af[t].us[i] = x1[row + t*16 + n];
            }
            const bf16x8 bw = *(const bf16x8*)&wbf[n*32 + q*8];
            #pragma unroll
            for (int t = 0; t < 4; t++) {
                fx4 d = {0.f,0.f,0.f,0.f};
                d = __builtin_amdgcn_mfma_f32_16x16x32_bf16(af[t].v, bw, d, 0, 0, 0);
                if (n < NKP) {
                    const uint2 o = make_uint2(pk2(d[0], d[1]), pk2(d[2], d[3]));
                    // ch-block XOR swizzle by (kp&3) (round-5, verified).
                    *(uint2*)&s_aggT[pl*AS + n*64 + ((t ^ (n & 3))<<4) + q*4] = o;
                }
            }
        }
    }
    __syncthreads();   // phase-1 region dead; union re-partitioned:

    short* s_x2bf   = (short*)s_un;                        // [16][XS]
    short* s_featbf = (short*)s_un + 16*XS;                // [16][FS]
    float* s_part   = (float*)((char*)s_un + 6656);        // [2][16][PS]

    for (int i = tid; i < 16*CIN; i += 512) {
        const int p = i / CIN, j = i % CIN;
        s_featbf[p*FS + j] = bfr(feat_in[(size_t)pbase*CIN + i]);
    }

    const int nlane = lane & 15, q = lane >> 4;
    // phase 2: x2 = lrelu(agg @ Wk). wave w -> col-tile (w&3), K-half (w>>2).
    {
        const int ct = w & 3, kh = w >> 2;
        fx4 acc = {0.f,0.f,0.f,0.f};
        const short* abase = &s_aggT[nlane*AS];
        const short* brw  = &WkT[(size_t)(ct*16 + nlane)*960 + kh*480];
        const int obase = kh*480 + q*8;
        for (int t = 0; t < 15; t++) {
            const int O  = obase + t*32;                  // logical K offset
            const int Os = O ^ (((O >> 6) & 3) << 4);     // match store swizzle
            const bf16x8 af = *(const bf16x8*)&abase[Os];
            const bf16x8 bf = *(const bf16x8*)&brw[t*32 + q*8];
            acc = __builtin_amdgcn_mfma_f32_16x16x32_bf16(af, bf, acc, 0, 0, 0);
        }
        float* pp = s_part + kh*(16*PS);
        #pragma unroll
        for (int r = 0; r < 4; r++)
            pp[(q*4+r)*PS + ct*16 + nlane] = acc[r];
    }
    __syncthreads();
    for (int i = tid; i < 1024; i += 512) {
        const int pt = i >> 6, c = i & 63;
        const float v = s_part[pt*PS + c] + s_part[16*PS + pt*PS + c];
        s_x2bf[pt*XS + c] = bfr(lrelu(v));
    }
    __syncthreads();

    // phase 3: out = lrelu([x2|feat] @ [W2;Ws]). wave w -> cols [16w,16w+16).
    fx4 acc0 = {0.f,0.f,0.f,0.f};
    {
        const short* b0r = &WcatT[(size_t)(w*16 + nlane)*KC];
        const short* xrow = &s_x2bf[nlane*XS];
        const short* frow = &s_featbf[nlane*FS];
        #pragma unroll
        for (int t = 0; t < KC/32; t++) {
            const int k0 = t*32 + q*8;
            const short* src = (t < 2) ? &xrow[k0] : &frow[k0 - 64];
            const bf16x8 af = *(const bf16x8*)src;
            const bf16x8 b0 = *(const bf16x8*)&b0r[k0];
            acc0 = __builtin_amdgcn_mfma_f32_16x16x32_bf16(af, b0, acc0, 0, 0, 0);
        }
        #pragma unroll
        for (int r = 0; r < 4; r++)
            out[(size_t)(pbase + q*4 + r)*128 + w*16 + nlane] = lrelu(acc0[r]);
    }

    if (FUSE) {
        // phase 4: x1out = lrelu(out @ W1) for the NEXT layer, in-block.
        __syncthreads();   // all phase-3 LDS reads done; re-alias s_un
        short* s_fout = (short*)s_un;   // [16][FOS]
        #pragma unroll
        for (int r = 0; r < 4; r++)
            s_fout[(q*4 + r)*FOS + w*16 + nlane] = bfr(lrelu(acc0[r]));
        __syncthreads();
        if (w < 4) {
            fx4 acc = {0.f,0.f,0.f,0.f};
            const short* arow = &s_fout[nlane*FOS];
            const short* brw  = &W1T[(size_t)(w*16 + nlane)*128];
            #pragma unroll
            for (int t = 0; t < 4; t++) {
                const int k0 = t*32 + q*8;
                const bf16x8 af = *(const bf16x8*)&arow[k0];
                const bf16x8 bf = *(const bf16x8*)&brw[k0];
                acc = __builtin_amdgcn_mfma_f32_16x16x32_bf16(af, bf, acc, 0, 0, 0);
            }
            #pragma unroll
            for (int r = 0; r < 4; r++)
                x1out[(size_t)(pbase + q*4 + r)*64 + w*16 + nlane] =
                    (unsigned short)bfr(lrelu(acc[r]));
        }
    }
}

// ---------------------------------------------------------------------------
__global__ __launch_bounds__(256) void k_vlad_a(
    const float* __restrict__ f, const float* __restrict__ wa,
    const int* __restrict__ m, float* __restrict__ a, float* __restrict__ sumA)
{
    __shared__ __align__(16) float s_fT[128*36 + 8];
    __shared__ float s_m[32];
    const int tid = threadIdx.x;
    const int pbase = blockIdx.x * 32;
    const int b = pbase >> 11;
    for (int i = tid; i < 32*128; i += 256) {
        const int p = i >> 7, j = i & 127;
        s_fT[j*36 + p] = f[(size_t)pbase*128 + i];
    }
    if (tid < 32) s_m[tid] = (m[pbase + tid] != 0) ? 0.f : 1.f;
    __syncthreads();
    const int w = tid >> 6, kc = tid & 63;
    const int pb = w * 8;
    float acc[8] = {0.f,0.f,0.f,0.f,0.f,0.f,0.f,0.f};
    for (int j = 0; j < 128; j++) {
        const float wv = wa[j*64 + kc];
        const float4 f0 = *(const float4*)&s_fT[j*36 + pb];
        const float4 f1 = *(const float4*)&s_fT[j*36 + pb + 4];
        acc[0] = fmaf(f0.x, wv, acc[0]); acc[1] = fmaf(f0.y, wv, acc[1]);
        acc[2] = fmaf(f0.z, wv, acc[2]); acc[3] = fmaf(f0.w, wv, acc[3]);
        acc[4] = fmaf(f1.x, wv, acc[4]); acc[5] = fmaf(f1.y, wv, acc[5]);
        acc[6] = fmaf(f1.z, wv, acc[6]); acc[7] = fmaf(f1.w, wv, acc[7]);
    }
    float part = 0.f;
    #pragma unroll
    for (int pl = 0; pl < 8; pl++) {
        float mx = acc[pl];
        #pragma unroll
        for (int off = 32; off > 0; off >>= 1) mx = fmaxf(mx, __shfl_xor(mx, off, 64));
        const float e = expf(acc[pl] - mx);
        float se = e;
        #pragma unroll
        for (int off = 32; off > 0; off >>= 1) se += __shfl_xor(se, off, 64);
        const float av = (e / se) * s_m[pb + pl];
        a[(size_t)(pbase + pb + pl)*64 + kc] = av;
        part += av;
    }
    atomicAdd(&sumA[b*64 + kc], part);
}

// ---------------------------------------------------------------------------
__global__ __launch_bounds__(256) void k_vlad_acc(
    const float* __restrict__ a, const float* __restrict__ f,
    float* __restrict__ vpart)
{
    __shared__ __align__(16) float s_a[32*64];
    __shared__ __align__(16) float s_f[32*128];
    const int b  = blockIdx.x >> 5;          // VCH=32
    const int ch = blockIdx.x & 31;
    const int n0 = ch * (N / VCH);
    const int tid = threadIdx.x;
    const int kc0 = (tid >> 5) * 8;
    const int d0  = (tid & 31) * 4;
    float acc[8][4];
    #pragma unroll
    for (int i = 0; i < 8; i++)
        #pragma unroll
        for (int j = 0; j < 4; j++) acc[i][j] = 0.f;
    for (int t = 0; t < N/VCH; t += 32) {
        __syncthreads();
        const size_t base = (size_t)(b*N + n0 + t);
        for (int i = tid; i < 32*64; i += 256)  s_a[i] = a[(base << 6) + i];
        for (int i = tid; i < 32*128; i += 256) s_f[i] = f[(base << 7) + i];
        __syncthreads();
        for (int n = 0; n < 32; n++) {
            const float4 a0 = *(const float4*)&s_a[n*64 + kc0];
            const float4 a1 = *(const float4*)&s_a[n*64 + kc0 + 4];
            const float4 fv = *(const float4*)&s_f[n*128 + d0];
            const float av[8] = {a0.x,a0.y,a0.z,a0.w,a1.x,a1.y,a1.z,a1.w};
            const float fw[4] = {fv.x,fv.y,fv.z,fv.w};
            #pragma unroll
            for (int i = 0; i < 8; i++)
                #pragma unroll
                for (int j = 0; j < 4; j++) acc[i][j] = fmaf(av[i], fw[j], acc[i][j]);
        }
    }
    float* vp = vpart + ((size_t)ch*B + b)*8192;
    #pragma unroll
    for (int i = 0; i < 8; i++)
        #pragma unroll
        for (int j = 0; j < 4; j++) vp[(kc0+i)*128 + d0 + j] = acc[i][j];
}

// ---------------------------------------------------------------------------
// Intra-normalize; also accumulates the per-batch global sum-of-squares.
__global__ __launch_bounds__(128) void k_vlad_norm(
    const float* __restrict__ vpart, const float* __restrict__ sumA,
    const float* __restrict__ centers, float* __restrict__ v,
    float* __restrict__ ssq)
{
    const int b = blockIdx.x >> 6, kc = blockIdx.x & 63, d = threadIdx.x;
    float acc = 0.f;
    #pragma unroll
    for (int c = 0; c < VCH; c++)
        acc += vpart[((size_t)c*B + b)*8192 + kc*128 + d];
    const float vv = acc - sumA[b*64 + kc] * centers[kc*128 + d];
    float s2 = vv*vv;
    #pragma unroll
    for (int off = 32; off > 0; off >>= 1) s2 += __shfl_xor(s2, off, 64);
    __shared__ float red[2];
    if ((d & 63) == 0) red[d >> 6] = s2;
    __syncthreads();
    const float tot = red[0] + red[1];
    const float s = sqrtf(tot) + 1e-8f;
    v[((size_t)b*64 + kc)*128 + d] = vv / s;
    if (d == 0) atomicAdd(&ssq[b], tot / (s*s));
}

// ---------------------------------------------------------------------------
__global__ __launch_bounds__(256) void k_proj(
    const float* __restrict__ v, const float* __restrict__ ssq,
    const float* __restrict__ proj, float* __restrict__ outacc)
{
    __shared__ __align__(16) float s_v[8*64];
    __shared__ float s_sc[8];
    const int jc = blockIdx.x, o = threadIdx.x;
    const int j0 = jc * 64;
    for (int i = o; i < 8*64; i += 256) {
        const int bb = i >> 6, jj = i & 63;
        s_v[i] = v[(size_t)bb*8192 + j0 + jj];
    }
    if (o < 8) s_sc[o] = 1.f / (sqrtf(ssq[o]) + 1e-8f);
    __syncthreads();
    float acc[8] = {0.f,0.f,0.f,0.f,0.f,0.f,0.f,0.f};
    for (int jj = 0; jj < 64; jj += 4) {
        float pv[4];
        #pragma unroll
        for (int q = 0; q < 4; q++) pv[q] = proj[(size_t)(j0+jj+q)*256 + o];
        #pragma unroll
        for (int bb = 0; bb < 8; bb++) {
            const float4 vv = *(const float4*)&s_v[bb*64 + jj];
            acc[bb] = fmaf(vv.x, pv[0], acc[bb]);
            acc[bb] = fmaf(vv.y, pv[1], acc[bb]);
            acc[bb] = fmaf(vv.z, pv[2], acc[bb]);
            acc[bb] = fmaf(vv.w, pv[3], acc[bb]);
        }
    }
    #pragma unroll
    for (int bb = 0; bb < 8; bb++) atomicAdd(&outacc[bb*256 + o], acc[bb] * s_sc[bb]);
}

__global__ __launch_bounds__(256) void k_outnorm(
    const float* __restrict__ outacc, float* __restrict__ out)
{
    const int b = blockIdx.x, o = threadIdx.x;
    const float val = outacc[b*256 + o];
    float s = val*val;
    #pragma unroll
    for (int off = 32; off > 0; off >>= 1) s += __shfl_xor(s, off, 64);
    __shared__ float red[4];
    if ((o & 63) == 0) red[o >> 6] = s;
    __syncthreads();
    const float tot = red[0] + red[1] + red[2] + red[3];
    out[b*256 + o] = val / (sqrtf(tot) + 1e-12f);
}

// ---------------------------------------------------------------------------
extern "C" void kernel_launch(void* const* d_in, const int* in_sizes, int n_in,
                              void* d_out, int out_size, void* d_ws, size_t ws_size,
                              hipStream_t stream)
{
    (void)in_sizes; (void)n_in; (void)out_size; (void)ws_size;
    const float* x     = (const float*)d_in[0];
    const int*   m     = (const int*)  d_in[1];
    const float* pn_w1 = (const float*)d_in[2];
    const float* pn_b1 = (const float*)d_in[3];
    const float* pn_w2 = (const float*)d_in[4];
    const float* pn_b2 = (const float*)d_in[5];
    const float* kp    = (const float*)d_in[6];
    const float* bw1[3] = {(const float*)d_in[7],  (const float*)d_in[11], (const float*)d_in[15]};
    const float* bwk[3] = {(const float*)d_in[8],  (const float*)d_in[12], (const float*)d_in[16]};
    const float* bw2[3] = {(const float*)d_in[9],  (const float*)d_in[13], (const float*)d_in[17]};
    const float* bws[3] = {(const float*)d_in[10], (const float*)d_in[14], (const float*)d_in[18]};
    const float* vlad_wa      = (const float*)d_in[19];
    const float* vlad_centers = (const float*)d_in[20];
    const float* vlad_proj    = (const float*)d_in[21];
    float* out = (float*)d_out;

    char* ws = (char*)d_ws;
    size_t off = 0;
    auto alloc = [&](size_t bytes) -> void* {
        void* p = ws + off;
        off = (off + bytes + 255) & ~(size_t)255;
        return p;
    };
    float4* coords4 = (float4*)alloc((size_t)BN*16);
    float*  feat0   = (float*)alloc((size_t)BN*64*4);
    int*    idxb    = (int*)  alloc((size_t)BN*KNBR*4);
    unsigned short* x1A = (unsigned short*)alloc((size_t)BN*64*2);  // bf16 ping
    unsigned short* x1B = (unsigned short*)alloc((size_t)BN*64*2);  // bf16 pong
    float*  fA      = (float*)alloc((size_t)BN*128*4);
    float*  fB      = (float*)alloc((size_t)BN*128*4);
    float*  abuf    = (float*)alloc((size_t)BN*64*4);
    float*  vbuf    = (float*)alloc((size_t)B*8192*4);
    // contiguous zero region (k_prep tail): sumA | outacc | ssqb | cntb
    float*  sumA    = (float*)alloc((size_t)B*64*4);    // 2048 B (256-aligned)
    float*  outacc  = (float*)alloc((size_t)B*256*4);   // 8192 B
    float*  ssqb    = (float*)alloc((size_t)B*4);       // padded to 256 B
    int*    cntb    = (int*)  alloc((size_t)B*4);
    int*    compact = (int*)alloc((size_t)BN*4);
    short*  wkT[3]  = {(short*)alloc(64*960*2), (short*)alloc(64*960*2), (short*)alloc(64*960*2)};
    short*  catT[3] = {(short*)alloc(128*192*2), (short*)alloc(128*192*2), (short*)alloc(128*192*2)};
    short*  w1T1    = (short*)alloc(64*128*2);
    short*  w1T2    = (short*)alloc(64*128*2);
    float*  vpart   = fB;   // fB dead after layer-2 reads it; 8 MB fits VCH=32 exactly

    k_prep<<<(3*61440 + 81920 + ZERON + 255)/256, 256, 0, stream>>>(
        bwk[0], bwk[1], bwk[2], bw2[0], bws[0], bw2[1], bws[1], bw2[2], bws[2],
        bw1[1], bw1[2],
        wkT[0], wkT[1], wkT[2], catT[0], catT[1], catT[2], w1T1, w1T2, sumA);

    k_compact<<<BN/256, 256, 0, stream>>>(m, compact, cntb, idxb);
    k_pointnet<<<BN/32, 256, 0, stream>>>(x, m, pn_w1, pn_b1, pn_w2, pn_b2, bw1[0],
                                          feat0, coords4, x1A);
    k_knn<<<B*256, 512, 0, stream>>>(coords4, compact, cntb, idxb);

    k_kpconv<64,true>  <<<BN/16, 512, 0, stream>>>(x1A, coords4, kp, idxb, feat0, wkT[0], catT[0], w1T1, x1B, fA);
    k_kpconv<128,true> <<<BN/16, 512, 0, stream>>>(x1B, coords4, kp, idxb, fA,    wkT[1], catT[1], w1T2, x1A, fB);
    k_kpconv<128,false><<<BN/16, 512, 0, stream>>>(x1A, coords4, kp, idxb, fB,    wkT[2], catT[2], nullptr, nullptr, fA);

    k_vlad_a<<<BN/32, 256, 0, stream>>>(fA, vlad_wa, m, abuf, sumA);
    k_vlad_acc<<<B*VCH, 256, 0, stream>>>(abuf, fA, vpart);
    k_vlad_norm<<<B*64, 128, 0, stream>>>(vpart, sumA, vlad_centers, vbuf, ssqb);
    k_proj<<<128, 256, 0, stream>>>(vbuf, ssqb, vlad_proj, outacc);
    k_outnorm<<<B, 256, 0, stream>>>(outacc, out);
}